// Round 9
// baseline (4232.114 us; speedup 1.0000x reference)
//
#include <hip/hip_runtime.h>
#include <hip/hip_cooperative_groups.h>
#include <stdint.h>

namespace cg = cooperative_groups;

// ---------------------------------------------------------------------------
// TAGConv(3 layers, K=2) + edge-weight norm + MLP link predictor.
// Round 9: chunked persistent SpMM — cooperative launch, all waves walk the
// same src-window (3.2MB, per-XCD-L2 resident) per chunk with grid.sync()
// between chunks; fp32 row accumulators live in registers across chunks.
// Per-row chunk offsets precomputed in k_norm (src-sorted rows + ballot).
// ---------------------------------------------------------------------------

#define D128 128
#define SPMM_BLOCKS 1792
#define SPMM_WAVES (SPMM_BLOCKS * 4)

typedef __bf16 v8bf __attribute__((ext_vector_type(8)));
typedef float v4f __attribute__((ext_vector_type(4)));
typedef uint32_t v4u __attribute__((ext_vector_type(4)));
typedef unsigned short ushort_t;

union BFU { v4u u; v8bf b; uint4 q; };

__device__ __forceinline__ uint32_t pack_hl(float f) {
  uint32_t hi = __float_as_uint(f) & 0xffff0000u;
  float lo = f - __uint_as_float(hi);
  return hi | (__float_as_uint(lo) >> 16);
}
__device__ __forceinline__ float unpack_hl(uint32_t p) {
  return __uint_as_float(p & 0xffff0000u) + __uint_as_float(p << 16);
}
__device__ __forceinline__ uint32_t f2bf_rn(float f) {
  uint32_t u = __float_as_uint(f);
  return (u + 0x7fffu + ((u >> 16) & 1u)) >> 16;
}
__device__ __forceinline__ float bflo(uint32_t u) { return __uint_as_float(u << 16); }
__device__ __forceinline__ float bfhi(uint32_t u) { return __uint_as_float(u & 0xffff0000u); }
__device__ __forceinline__ uint32_t bfmul2(uint32_t a, uint32_t b) {
  return f2bf_rn(bflo(a) * bflo(b)) | (f2bf_rn(bfhi(a) * bfhi(b)) << 16);
}

// ---------------- sort-based graph build ------------------------------------

__global__ void k_hist2(const int* __restrict__ src, const int* __restrict__ dst,
                        int E, uint32_t* __restrict__ histD,
                        uint32_t* __restrict__ histS) {
  __shared__ uint32_t hd[256], hs[256];
  int t = threadIdx.x;
  hd[t] = 0; hs[t] = 0;
  __syncthreads();
  for (int e = blockIdx.x * 256 + t; e < E; e += gridDim.x * 256) {
    atomicAdd(&hd[((unsigned)dst[e]) >> 8], 1u);
    atomicAdd(&hs[((unsigned)src[e]) >> 8], 1u);
  }
  __syncthreads();
  if (hd[t]) atomicAdd(&histD[t], hd[t]);
  if (hs[t]) atomicAdd(&histS[t], hs[t]);
}

__global__ void k_scan2(const uint32_t* __restrict__ histD,
                        const uint32_t* __restrict__ histS,
                        uint32_t* __restrict__ curD, uint32_t* __restrict__ baseD,
                        uint32_t* __restrict__ curS, uint32_t* __restrict__ baseS,
                        int* __restrict__ rowptr, int N, int E) {
  __shared__ uint32_t ws[4];
  int t = threadIdx.x;
  int lane = t & 63, wid = t >> 6;
  for (int which = 0; which < 2; ++which) {
    uint32_t v = which ? histS[t] : histD[t];
    uint32_t x = v;
#pragma unroll
    for (int d = 1; d < 64; d <<= 1) {
      uint32_t y = (uint32_t)__shfl_up((int)x, d);
      if (lane >= d) x += y;
    }
    if (lane == 63) ws[wid] = x;
    __syncthreads();
    if (t == 0) {
      uint32_t a = 0;
#pragma unroll
      for (int k = 0; k < 4; ++k) { uint32_t tmp = ws[k]; ws[k] = a; a += tmp; }
    }
    __syncthreads();
    uint32_t ex = x - v + ws[wid];
    if (which == 0) {
      curD[t] = ex; baseD[t] = ex;
      if (t == 0) baseD[256] = (uint32_t)E;
    } else {
      curS[t] = ex; baseS[t] = ex;
      if (t == 0) baseS[256] = (uint32_t)E;
    }
    __syncthreads();
  }
  if (t == 0) rowptr[N] = E;
}

__global__ void k_part_dst(const int* __restrict__ src, const int* __restrict__ dst,
                           const float* __restrict__ w, int E,
                           uint32_t* __restrict__ curD, uint2* __restrict__ bufD) {
  __shared__ uint32_t lh[256], lbase[256];
  int t = threadIdx.x;
  int per = (E + gridDim.x - 1) / gridDim.x;
  int e0 = blockIdx.x * per, e1 = min(e0 + per, E);
  lh[t] = 0;
  __syncthreads();
  for (int e = e0 + t; e < e1; e += 256) atomicAdd(&lh[((unsigned)dst[e]) >> 8], 1u);
  __syncthreads();
  uint32_t c = lh[t];
  lbase[t] = c ? atomicAdd(&curD[t], c) : 0u;
  __syncthreads();
  lh[t] = 0;
  __syncthreads();
  for (int e = e0 + t; e < e1; e += 256) {
    int d = dst[e];
    uint32_t bin = ((unsigned)d) >> 8;
    uint32_t pos = lbase[bin] + atomicAdd(&lh[bin], 1u);
    bufD[pos] = make_uint2((((unsigned)d & 255u) << 16) | (unsigned)src[e],
                           __float_as_uint(w[e]));
  }
}

__global__ void k_part_src(const int* __restrict__ src, const float* __restrict__ w,
                           int E, uint32_t* __restrict__ curS,
                           uint2* __restrict__ bufS) {
  __shared__ uint32_t lh[256], lbase[256];
  int t = threadIdx.x;
  int per = (E + gridDim.x - 1) / gridDim.x;
  int e0 = blockIdx.x * per, e1 = min(e0 + per, E);
  lh[t] = 0;
  __syncthreads();
  for (int e = e0 + t; e < e1; e += 256) atomicAdd(&lh[((unsigned)src[e]) >> 8], 1u);
  __syncthreads();
  uint32_t c = lh[t];
  lbase[t] = c ? atomicAdd(&curS[t], c) : 0u;
  __syncthreads();
  lh[t] = 0;
  __syncthreads();
  for (int e = e0 + t; e < e1; e += 256) {
    int s = src[e];
    uint32_t bin = ((unsigned)s) >> 8;
    uint32_t pos = lbase[bin] + atomicAdd(&lh[bin], 1u);
    bufS[pos] = make_uint2((unsigned)s, __float_as_uint(w[e]));
  }
}

__global__ void k_sub_dst(const uint2* __restrict__ bufD,
                          const uint32_t* __restrict__ baseD,
                          uint2* __restrict__ esw, int* __restrict__ rowptr, int N) {
  __shared__ uint32_t lh[256], cur[256], ws4[4];
  int hb = blockIdx.x, t = threadIdx.x;
  int b = (int)baseD[hb], e = (int)baseD[hb + 1];
  lh[t] = 0;
  __syncthreads();
  for (int i = b + t; i < e; i += 256) atomicAdd(&lh[(bufD[i].x >> 16) & 255u], 1u);
  __syncthreads();
  uint32_t v = lh[t], x = v;
  int lane = t & 63, wid = t >> 6;
#pragma unroll
  for (int d = 1; d < 64; d <<= 1) {
    uint32_t y = (uint32_t)__shfl_up((int)x, d);
    if (lane >= d) x += y;
  }
  if (lane == 63) ws4[wid] = x;
  __syncthreads();
  if (t == 0) {
    uint32_t a = 0;
#pragma unroll
    for (int k = 0; k < 4; ++k) { uint32_t tmp = ws4[k]; ws4[k] = a; a += tmp; }
  }
  __syncthreads();
  uint32_t ex = x - v + ws4[wid];
  cur[t] = ex;
  int d = hb * 256 + t;
  if (d < N) rowptr[d] = b + (int)ex;
  __syncthreads();
  for (int i = b + t; i < e; i += 256) {
    uint2 el = bufD[i];
    uint32_t lo = (el.x >> 16) & 255u;
    uint32_t pos = atomicAdd(&cur[lo], 1u);
    esw[b + pos] = make_uint2(el.x & 0xffffu, el.y);
  }
}

__global__ void k_sub_src(const uint2* __restrict__ bufS,
                          const uint32_t* __restrict__ baseS,
                          float* __restrict__ deg_out, int N) {
  __shared__ float acc[256];
  int hb = blockIdx.x, t = threadIdx.x;
  acc[t] = 0.f;
  __syncthreads();
  int b = (int)baseS[hb], e = (int)baseS[hb + 1];
  for (int i = b + t; i < e; i += 256)
    atomicAdd(&acc[bufS[i].x & 255u], __uint_as_float(bufS[i].y));
  __syncthreads();
  int s = hb * 256 + t;
  if (s < N) deg_out[s] = acc[t];
}

// deg_in + normalize + bitonic sort by src + per-row chunk offsets (src < n/4,
// n/2, 3n/4 positions, packed 3xu8; clamped-monotone so partition stays valid).
__global__ void k_norm(const float* __restrict__ deg_out, const int* __restrict__ rowptr,
                       uint2* __restrict__ esw, uint32_t* __restrict__ chunkoff,
                       int n) {
  int row = blockIdx.x * 4 + (threadIdx.x >> 6);
  if (row >= n) return;
  int lane = threadIdx.x & 63;
  int b0 = rowptr[row];
  int cnt = rowptr[row + 1] - b0;
  uint32_t q1 = (uint32_t)(n / 4), q2 = (uint32_t)(n / 2), q3 = (uint32_t)((3 * (long long)n) / 4);
  if (cnt <= 64) {
    uint32_t key = 0xffffffffu;
    float val = 0.f;
    if (lane < cnt) {
      uint2 e = esw[b0 + lane];
      key = e.x;
      val = __uint_as_float(e.y);
    }
    float s = val;
#pragma unroll
    for (int d = 32; d; d >>= 1) s += __shfl_xor(s, d);
#pragma unroll
    for (int k = 2; k <= 64; k <<= 1) {
#pragma unroll
      for (int j = k >> 1; j > 0; j >>= 1) {
        uint32_t ok = (uint32_t)__shfl_xor((int)key, j);
        float ov = __shfl_xor(val, j);
        bool asc = ((lane & k) == 0);
        bool lower = ((lane & j) == 0);
        bool take_min = (lower == asc);
        bool sw = take_min ? (ok < key) : (ok > key);
        if (sw) { key = ok; val = ov; }
      }
    }
    uint32_t p1 = (uint32_t)__popcll(__ballot(key < q1));
    uint32_t p2 = (uint32_t)__popcll(__ballot(key < q2));
    uint32_t p3 = (uint32_t)__popcll(__ballot(key < q3));
    if (lane == 0) chunkoff[row] = p1 | (p2 << 8) | (p3 << 16);
    if (lane < cnt) {
      float dout = deg_out[key];
      float nw = val / sqrtf(fmaxf(dout * s, 1e-12f));
      esw[b0 + lane] = make_uint2(key, __float_as_uint(nw));
    }
  } else {
    float s = 0.f;
    int c1 = 0, c2 = 0, c3 = 0;
    for (int i = lane; i < cnt; i += 64) {
      uint2 e = esw[b0 + i];
      s += __uint_as_float(e.y);
      c1 += (e.x < q1); c2 += (e.x < q2); c3 += (e.x < q3);
    }
#pragma unroll
    for (int d = 32; d; d >>= 1) {
      s += __shfl_xor(s, d);
      c1 += __shfl_xor(c1, d);
      c2 += __shfl_xor(c2, d);
      c3 += __shfl_xor(c3, d);
    }
    if (lane == 0) {
      uint32_t p1 = (uint32_t)min(c1, 255), p2 = (uint32_t)min(c2, 255),
               p3 = (uint32_t)min(c3, 255);
      chunkoff[row] = p1 | (p2 << 8) | (p3 << 16);
    }
    for (int i = lane; i < cnt; i += 64) {
      uint2 e = esw[b0 + i];
      float dout = deg_out[e.x];
      float nw = __uint_as_float(e.y) / sqrtf(fmaxf(dout * s, 1e-12f));
      esw[b0 + i] = make_uint2(e.x, __float_as_uint(nw));
    }
  }
}

// ---------------- format conversion ----------------

__global__ void k_pack4(const float* __restrict__ in, uint32_t* __restrict__ Xp,
                        uint32_t* __restrict__ Xb, int n4) {
  int i = blockIdx.x * 256 + threadIdx.x;
  if (i >= n4) return;
  float4 f = ((const float4*)in)[i];
  ((uint4*)Xp)[i] = make_uint4(pack_hl(f.x), pack_hl(f.y), pack_hl(f.z), pack_hl(f.w));
  uint2 b;
  b.x = f2bf_rn(f.x) | (f2bf_rn(f.y) << 16);
  b.y = f2bf_rn(f.z) | (f2bf_rn(f.w) << 16);
  ((uint2*)Xb)[i] = b;
}

__global__ void k_packW(const float* __restrict__ p0, const float* __restrict__ p1,
                        const float* __restrict__ p2, const float* __restrict__ p3,
                        const float* __restrict__ p4, ushort_t* __restrict__ out) {
  int i = blockIdx.x * 256 + threadIdx.x;
  if (i >= 180224) return;
  float f;
  if (i < 49152) f = p0[i];
  else if (i < 98304) f = p1[i - 49152];
  else if (i < 147456) f = p2[i - 98304];
  else if (i < 163840) f = p3[i - 147456];
  else f = p4[i - 163840];
  out[i] = (ushort_t)f2bf_rn(f);
}

// ---------------- chunked persistent SpMM (cooperative) ----------------------
// All 7168 waves co-resident. Each wave owns up to 8 strided rows, fp32
// accumulators in registers. Chunk c processes edges with src in window c
// (3.2MB of X -> per-XCD L2 resident); grid.sync() keeps the whole chip in
// the same window. Edge lists ride the scalar path (wave-uniform rows).

__global__ __launch_bounds__(256, 8) void k_spmm_coop(
    const uint32_t* __restrict__ X, uint32_t* __restrict__ Y,
    const uint2* __restrict__ esw, const int* __restrict__ rowptr,
    const uint32_t* __restrict__ chunkoff, int n) {
  cg::grid_group grid = cg::this_grid();
  const int lane = threadIdx.x & 63;
  int gw = (int)(blockIdx.x * 4 + (threadIdx.x >> 6));
  gw = __builtin_amdgcn_readfirstlane(gw);
  const int W = SPMM_WAVES;

  int b0s[8], cnts[8];
  uint32_t offs[8];
#pragma unroll
  for (int k = 0; k < 8; ++k) {
    int row = gw + k * W;
    if (row < n) {
      b0s[k] = rowptr[row];
      cnts[k] = rowptr[row + 1] - b0s[k];
      offs[k] = chunkoff[row];
    } else {
      b0s[k] = 0; cnts[k] = 0; offs[k] = 0;
    }
  }
  float a0[8], a1[8];
#pragma unroll
  for (int k = 0; k < 8; ++k) { a0[k] = 0.f; a1[k] = 0.f; }

  for (int c = 0; c < 4; ++c) {
#pragma unroll
    for (int k = 0; k < 8; ++k) {
      int i0 = (c == 0) ? 0 : (int)((offs[k] >> (8 * c - 8)) & 255u);
      int i1 = (c == 3) ? cnts[k] : (int)((offs[k] >> (8 * c)) & 255u);
      const uint2* __restrict__ ep = esw + b0s[k];
      int i = i0;
      for (; i + 4 <= i1; i += 4) {
        uint2 e0 = ep[i], e1 = ep[i + 1], e2 = ep[i + 2], e3 = ep[i + 3];
        uint32_t u0 = X[(size_t)e0.x * 64 + lane];
        uint32_t u1 = X[(size_t)e1.x * 64 + lane];
        uint32_t u2 = X[(size_t)e2.x * 64 + lane];
        uint32_t u3 = X[(size_t)e3.x * 64 + lane];
        float w0 = __uint_as_float(e0.y), w1 = __uint_as_float(e1.y);
        float w2 = __uint_as_float(e2.y), w3 = __uint_as_float(e3.y);
        a0[k] = fmaf(w0, bflo(u0), a0[k]); a1[k] = fmaf(w0, bfhi(u0), a1[k]);
        a0[k] = fmaf(w1, bflo(u1), a0[k]); a1[k] = fmaf(w1, bfhi(u1), a1[k]);
        a0[k] = fmaf(w2, bflo(u2), a0[k]); a1[k] = fmaf(w2, bfhi(u2), a1[k]);
        a0[k] = fmaf(w3, bflo(u3), a0[k]); a1[k] = fmaf(w3, bfhi(u3), a1[k]);
      }
      for (; i < i1; ++i) {
        uint2 e = ep[i];
        uint32_t u = X[(size_t)e.x * 64 + lane];
        float w0 = __uint_as_float(e.y);
        a0[k] = fmaf(w0, bflo(u), a0[k]);
        a1[k] = fmaf(w0, bfhi(u), a1[k]);
      }
    }
    if (c < 3) grid.sync();
  }

#pragma unroll
  for (int k = 0; k < 8; ++k) {
    int row = gw + k * W;
    if (row < n)
      Y[(size_t)row * 64 + lane] = f2bf_rn(a0[k]) | (f2bf_rn(a1[k]) << 16);
  }
}

// ---------------- MFMA GEMM --------------------------------------------------

__device__ __forceinline__ void build_frags_v(uint4 q0, uint4 q1, v8bf& hi, v8bf& lo) {
  BFU uh, ul;
  uh.u[0] = (q0.x >> 16) | (q0.y & 0xffff0000u);
  uh.u[1] = (q0.z >> 16) | (q0.w & 0xffff0000u);
  uh.u[2] = (q1.x >> 16) | (q1.y & 0xffff0000u);
  uh.u[3] = (q1.z >> 16) | (q1.w & 0xffff0000u);
  ul.u[0] = (q0.x & 0xffffu) | (q0.y << 16);
  ul.u[1] = (q0.z & 0xffffu) | (q0.w << 16);
  ul.u[2] = (q1.x & 0xffffu) | (q1.y << 16);
  ul.u[3] = (q1.z & 0xffffu) | (q1.w << 16);
  hi = uh.b;
  lo = ul.b;
}

__global__ __launch_bounds__(256) void k_gemm(
    const uint32_t* __restrict__ F0hl, const uint32_t* __restrict__ F1b,
    const uint32_t* __restrict__ F2b, const ushort_t* __restrict__ Wb,
    const float* __restrict__ bias, int relu, int M,
    uint32_t* __restrict__ outp, ushort_t* __restrict__ outh,
    float* __restrict__ outf) {
  __shared__ ushort_t Wl[128 * 128];  // 32 KB swizzled
  const int t = threadIdx.x;
  const int lane = t & 63;
  const int wave = t >> 6;
  const int wr = wave >> 1, wc = wave & 1;
  const int row0 = blockIdx.x * 64;
  const int l15 = lane & 15;
  const int kg = lane >> 4;

  int arow[2];
#pragma unroll
  for (int mr = 0; mr < 2; ++mr)
    arow[mr] = min(row0 + wr * 32 + mr * 16 + l15, M - 1);
  int wcol[4];
  float bv[4];
#pragma unroll
  for (int nr = 0; nr < 4; ++nr) {
    wcol[nr] = wc * 64 + nr * 16 + l15;
    bv[nr] = bias[wcol[nr]];
  }

  const uint32_t* __restrict__ F0r0 = F0hl + (size_t)arow[0] * D128 + kg * 8;
  const uint32_t* __restrict__ F0r1 = F0hl + (size_t)arow[1] * D128 + kg * 8;
  const uint32_t* __restrict__ F1r0 = F1b + (size_t)arow[0] * 64 + kg * 4;
  const uint32_t* __restrict__ F1r1 = F1b + (size_t)arow[1] * 64 + kg * 4;
  const uint32_t* __restrict__ F2r0 = F2b + (size_t)arow[0] * 64 + kg * 4;
  const uint32_t* __restrict__ F2r1 = F2b + (size_t)arow[1] * 64 + kg * 4;

  v4f acc[2][4];
#pragma unroll
  for (int mr = 0; mr < 2; ++mr)
#pragma unroll
    for (int nr = 0; nr < 4; ++nr) acc[mr][nr] = (v4f){0.f, 0.f, 0.f, 0.f};

  const int sc = t >> 1;
  const int sh = t & 1;
  const ushort_t* gpW = Wb + (size_t)sc * 384 + sh * 64;
  char* WlBase = (char*)Wl + sc * 256;

  // ---------------- seg0 (hi/lo plane, 2 MFMA per frag) ----------------
  uint4 f0[4][2][2];
#pragma unroll
  for (int kc = 0; kc < 2; ++kc) {
    f0[kc][0][0] = *(const uint4*)(F0r0 + kc * 32);
    f0[kc][0][1] = *(const uint4*)(F0r0 + kc * 32 + 4);
    f0[kc][1][0] = *(const uint4*)(F0r1 + kc * 32);
    f0[kc][1][1] = *(const uint4*)(F0r1 + kc * 32 + 4);
  }
  __syncthreads();
  {
    const ushort_t* gp = gpW;
#pragma unroll
    for (int gi = 0; gi < 8; ++gi) {
      int gg = sh * 8 + gi;
      uint4 v = *(const uint4*)(gp + gi * 8);
      *(uint4*)(WlBase + ((gg ^ (sc & 7)) * 16)) = v;
    }
  }
  __syncthreads();
#pragma unroll
  for (int kc = 0; kc < 4; ++kc) {
    if (kc < 2) {
      f0[kc + 2][0][0] = *(const uint4*)(F0r0 + (kc + 2) * 32);
      f0[kc + 2][0][1] = *(const uint4*)(F0r0 + (kc + 2) * 32 + 4);
      f0[kc + 2][1][0] = *(const uint4*)(F0r1 + (kc + 2) * 32);
      f0[kc + 2][1][1] = *(const uint4*)(F0r1 + (kc + 2) * 32 + 4);
    }
    v8bf ah[2], al[2];
#pragma unroll
    for (int mr = 0; mr < 2; ++mr)
      build_frags_v(f0[kc][mr][0], f0[kc][mr][1], ah[mr], al[mr]);
#pragma unroll
    for (int nr = 0; nr < 4; ++nr) {
      int col = wcol[nr];
      int g = (kc << 2) + kg;
      v8bf bf = *(const v8bf*)((const char*)Wl + col * 256 + ((g ^ (col & 7)) * 16));
#pragma unroll
      for (int mr = 0; mr < 2; ++mr) {
        acc[mr][nr] = __builtin_amdgcn_mfma_f32_16x16x32_bf16(ah[mr], bf, acc[mr][nr], 0, 0, 0);
        acc[mr][nr] = __builtin_amdgcn_mfma_f32_16x16x32_bf16(al[mr], bf, acc[mr][nr], 0, 0, 0);
      }
    }
  }

  // ---------------- seg1, seg2 (bf16 planes, full preload) ----------------
#pragma unroll
  for (int seg = 1; seg < 3; ++seg) {
    const uint32_t* __restrict__ Fr0 = (seg == 1) ? F1r0 : F2r0;
    const uint32_t* __restrict__ Fr1 = (seg == 1) ? F1r1 : F2r1;
    uint4 fb[4][2];
#pragma unroll
    for (int kc = 0; kc < 4; ++kc) {
      fb[kc][0] = *(const uint4*)(Fr0 + kc * 16);
      fb[kc][1] = *(const uint4*)(Fr1 + kc * 16);
    }
    __syncthreads();
    {
      const ushort_t* gp = gpW + seg * 128;
#pragma unroll
      for (int gi = 0; gi < 8; ++gi) {
        int gg = sh * 8 + gi;
        uint4 v = *(const uint4*)(gp + gi * 8);
        *(uint4*)(WlBase + ((gg ^ (sc & 7)) * 16)) = v;
      }
    }
    __syncthreads();
#pragma unroll
    for (int kc = 0; kc < 4; ++kc) {
      v8bf af[2];
      {
        BFU u0, u1;
        u0.q = fb[kc][0];
        u1.q = fb[kc][1];
        af[0] = u0.b;
        af[1] = u1.b;
      }
#pragma unroll
      for (int nr = 0; nr < 4; ++nr) {
        int col = wcol[nr];
        int g = (kc << 2) + kg;
        v8bf bf = *(const v8bf*)((const char*)Wl + col * 256 + ((g ^ (col & 7)) * 16));
#pragma unroll
        for (int mr = 0; mr < 2; ++mr)
          acc[mr][nr] = __builtin_amdgcn_mfma_f32_16x16x32_bf16(af[mr], bf, acc[mr][nr], 0, 0, 0);
      }
    }
  }

  __syncthreads();  // all reads done before (possibly aliased) epilogue writes

#pragma unroll
  for (int mr = 0; mr < 2; ++mr) {
#pragma unroll
    for (int nr = 0; nr < 4; ++nr) {
      v4f a = acc[mr][nr];
#pragma unroll
      for (int r = 0; r < 4; ++r) {
        int row = row0 + wr * 32 + mr * 16 + kg * 4 + r;
        if (row < M) {
          float v = a[r] + bv[nr];
          if (relu) v = fmaxf(v, 0.f);
          size_t o = (size_t)row * D128 + wcol[nr];
          if (outp) outp[o] = pack_hl(v);
          if (outh) outh[o] = (ushort_t)f2bf_rn(v);
          if (outf) outf[o] = v;
        }
      }
    }
  }
}

// ---------------- fused predictor (128 pairs/block, 2 chunks) ----------------

__global__ __launch_bounds__(256) void k_pred(
    const uint32_t* __restrict__ Hb, const int* __restrict__ pos_src,
    const int* __restrict__ pos_dst, const int* __restrict__ neg_src,
    const int* __restrict__ neg_dst, const ushort_t* __restrict__ W1,
    const ushort_t* __restrict__ W2, const float* __restrict__ b1,
    const float* __restrict__ b2, const float* __restrict__ w3,
    const float* __restrict__ b3, int P, float* __restrict__ out) {
  __shared__ ushort_t Wl[128 * 128];
  const int t = threadIdx.x;
  const int lane = t & 63;
  const int wave = t >> 6;
  const int l15 = lane & 15;
  const int kg = lane >> 4;
  const int P2 = 2 * P;

  const int qA = blockIdx.x * 128 + wave * 16 + l15;
  const int qB = qA + 64;
  const bool vA = qA < P2, vB = qB < P2;
  const int qcA = vA ? qA : (P2 - 1);
  const int qcB = vB ? qB : (P2 - 1);
  const int iaA = (qcA < P) ? pos_src[qcA] : neg_src[qcA - P];
  const int ibA = (qcA < P) ? pos_dst[qcA] : neg_dst[qcA - P];
  const int iaB = (qcB < P) ? pos_src[qcB] : neg_src[qcB - P];
  const int ibB = (qcB < P) ? pos_dst[qcB] : neg_dst[qcB - P];

  const int sc = t >> 1;
  const int sh = t & 1;

  // ---- stage W1 ----
  {
    const ushort_t* gp = W1 + sc * 128 + sh * 64;
#pragma unroll
    for (int gi = 0; gi < 8; ++gi) {
      int gg = sh * 8 + gi;
      uint4 v = *(const uint4*)(gp + gi * 8);
      *(uint4*)((char*)Wl + sc * 256 + ((gg ^ (sc & 7)) * 16)) = v;
    }
  }

  // ---- gather both chunks (32 independent 16B loads in flight) ----
  uint4 gaA[4], gbA[4], gaB[4], gbB[4];
#pragma unroll
  for (int kc = 0; kc < 4; ++kc) {
    gaA[kc] = *(const uint4*)(Hb + (size_t)iaA * 64 + kc * 16 + kg * 4);
    gbA[kc] = *(const uint4*)(Hb + (size_t)ibA * 64 + kc * 16 + kg * 4);
    gaB[kc] = *(const uint4*)(Hb + (size_t)iaB * 64 + kc * 16 + kg * 4);
    gbB[kc] = *(const uint4*)(Hb + (size_t)ibB * 64 + kc * 16 + kg * 4);
  }
  v8bf zfA[4], zfB[4];
#pragma unroll
  for (int kc = 0; kc < 4; ++kc) {
    BFU zA, zB;
    zA.u[0] = bfmul2(gaA[kc].x, gbA[kc].x);
    zA.u[1] = bfmul2(gaA[kc].y, gbA[kc].y);
    zA.u[2] = bfmul2(gaA[kc].z, gbA[kc].z);
    zA.u[3] = bfmul2(gaA[kc].w, gbA[kc].w);
    zB.u[0] = bfmul2(gaB[kc].x, gbB[kc].x);
    zB.u[1] = bfmul2(gaB[kc].y, gbB[kc].y);
    zB.u[2] = bfmul2(gaB[kc].z, gbB[kc].z);
    zB.u[3] = bfmul2(gaB[kc].w, gbB[kc].w);
    zfA[kc] = zA.b;
    zfB[kc] = zB.b;
  }
  __syncthreads();

  // ---- layer 1, chunk A then chunk B ----
  uint32_t pkA[8][2], pkB[8][2];
  {
    v4f acc1[8];
#pragma unroll
    for (int nr = 0; nr < 8; ++nr) acc1[nr] = (v4f){0.f, 0.f, 0.f, 0.f};
#pragma unroll
    for (int kc = 0; kc < 4; ++kc) {
#pragma unroll
      for (int nr = 0; nr < 8; ++nr) {
        int c = nr * 16 + l15;
        int g = 4 * kc + kg;
        v8bf wf = *(const v8bf*)((const char*)Wl + c * 256 + ((g ^ (c & 7)) * 16));
        acc1[nr] = __builtin_amdgcn_mfma_f32_16x16x32_bf16(wf, zfA[kc], acc1[nr], 0, 0, 0);
      }
    }
#pragma unroll
    for (int nr = 0; nr < 8; ++nr) {
      float v0 = fmaxf(acc1[nr][0] + b1[nr * 16 + kg * 4 + 0], 0.f);
      float v1 = fmaxf(acc1[nr][1] + b1[nr * 16 + kg * 4 + 1], 0.f);
      float v2 = fmaxf(acc1[nr][2] + b1[nr * 16 + kg * 4 + 2], 0.f);
      float v3 = fmaxf(acc1[nr][3] + b1[nr * 16 + kg * 4 + 3], 0.f);
      pkA[nr][0] = f2bf_rn(v0) | (f2bf_rn(v1) << 16);
      pkA[nr][1] = f2bf_rn(v2) | (f2bf_rn(v3) << 16);
    }
  }
  {
    v4f acc1[8];
#pragma unroll
    for (int nr = 0; nr < 8; ++nr) acc1[nr] = (v4f){0.f, 0.f, 0.f, 0.f};
#pragma unroll
    for (int kc = 0; kc < 4; ++kc) {
#pragma unroll
      for (int nr = 0; nr < 8; ++nr) {
        int c = nr * 16 + l15;
        int g = 4 * kc + kg;
        v8bf wf = *(const v8bf*)((const char*)Wl + c * 256 + ((g ^ (c & 7)) * 16));
        acc1[nr] = __builtin_amdgcn_mfma_f32_16x16x32_bf16(wf, zfB[kc], acc1[nr], 0, 0, 0);
      }
    }
#pragma unroll
    for (int nr = 0; nr < 8; ++nr) {
      float v0 = fmaxf(acc1[nr][0] + b1[nr * 16 + kg * 4 + 0], 0.f);
      float v1 = fmaxf(acc1[nr][1] + b1[nr * 16 + kg * 4 + 1], 0.f);
      float v2 = fmaxf(acc1[nr][2] + b1[nr * 16 + kg * 4 + 2], 0.f);
      float v3 = fmaxf(acc1[nr][3] + b1[nr * 16 + kg * 4 + 3], 0.f);
      pkB[nr][0] = f2bf_rn(v0) | (f2bf_rn(v1) << 16);
      pkB[nr][1] = f2bf_rn(v2) | (f2bf_rn(v3) << 16);
    }
  }

  // ---- restage W2 ----
  __syncthreads();
  {
    const ushort_t* gp = W2 + sc * 128 + sh * 64;
#pragma unroll
    for (int gi = 0; gi < 8; ++gi) {
      int gg = sh * 8 + gi;
      uint4 v = *(const uint4*)(gp + gi * 8);
      *(uint4*)((char*)Wl + sc * 256 + ((gg ^ (sc & 7)) * 16)) = v;
    }
  }
  __syncthreads();

  // ---- layer 2 + dot, chunk A then chunk B ----
#pragma unroll
  for (int chunk = 0; chunk < 2; ++chunk) {
    v4f acc2[8];
#pragma unroll
    for (int nr = 0; nr < 8; ++nr) acc2[nr] = (v4f){0.f, 0.f, 0.f, 0.f};
#pragma unroll
    for (int kc = 0; kc < 4; ++kc) {
      BFU y;
#pragma unroll
      for (int d = 0; d < 4; ++d) {
        int srcLane = l15 + 16 * ((kg & 1) * 2 + (d >> 1));
        uint32_t w0, w1;
        if (chunk == 0) {
          w0 = (uint32_t)__shfl((int)pkA[2 * kc][d & 1], srcLane);
          w1 = (uint32_t)__shfl((int)pkA[2 * kc + 1][d & 1], srcLane);
        } else {
          w0 = (uint32_t)__shfl((int)pkB[2 * kc][d & 1], srcLane);
          w1 = (uint32_t)__shfl((int)pkB[2 * kc + 1][d & 1], srcLane);
        }
        y.u[d] = (kg & 2) ? w1 : w0;
      }
#pragma unroll
      for (int nr = 0; nr < 8; ++nr) {
        int c = nr * 16 + l15;
        int g = 4 * kc + kg;
        v8bf wf = *(const v8bf*)((const char*)Wl + c * 256 + ((g ^ (c & 7)) * 16));
        acc2[nr] = __builtin_amdgcn_mfma_f32_16x16x32_bf16(wf, y.b, acc2[nr], 0, 0, 0);
      }
    }
    float s = 0.f;
#pragma unroll
    for (int nr = 0; nr < 8; ++nr) {
#pragma unroll
      for (int r = 0; r < 4; ++r) {
        int c = nr * 16 + kg * 4 + r;
        s += fmaxf(acc2[nr][r] + b2[c], 0.f) * w3[c];
      }
    }
    s += __shfl_xor(s, 16);
    s += __shfl_xor(s, 32);
    if (chunk == 0) {
      if (vA && kg == 0) out[qA] = s + b3[0];
    } else {
      if (vB && kg == 0) out[qB] = s + b3[0];
    }
  }
}

// ---------------- launch ----------------

extern "C" void kernel_launch(void* const* d_in, const int* in_sizes, int n_in,
                              void* d_out, int out_size, void* d_ws, size_t ws_size,
                              hipStream_t stream) {
  const float* x = (const float*)d_in[0];
  const float* w = (const float*)d_in[1];
  const int* src = (const int*)d_in[2];
  const int* dst = (const int*)d_in[3];
  const int* pos_src = (const int*)d_in[4];
  const int* pos_dst = (const int*)d_in[5];
  const int* neg_src = (const int*)d_in[6];
  const int* neg_dst = (const int*)d_in[7];
  const float* W0 = (const float*)d_in[8];
  const float* b0 = (const float*)d_in[9];
  const float* W1 = (const float*)d_in[10];
  const float* b1 = (const float*)d_in[11];
  const float* W2 = (const float*)d_in[12];
  const float* b2 = (const float*)d_in[13];
  const float* Wp1 = (const float*)d_in[14];
  const float* bp1 = (const float*)d_in[15];
  const float* Wp2 = (const float*)d_in[16];
  const float* bp2 = (const float*)d_in[17];
  const float* Wp3 = (const float*)d_in[18];
  const float* bp3 = (const float*)d_in[19];

  const int N = in_sizes[0] / D128;
  const int E = in_sizes[1];
  const int P = in_sizes[4];

  float* out = (float*)d_out;
  float* h_fin = out + 2 * (size_t)P;   // [N,128] fp32 final h (d_out)
  uint32_t* Hp = (uint32_t*)h_fin;      // reused as hi/lo h1 scratch

  char* p = (char*)d_ws;
#define WALLOC(T, name, bytes) \
  T name = (T)p;               \
  p += (((size_t)(bytes) + 255) & ~(size_t)255);
  WALLOC(uint32_t*, meta, (size_t)(4 * 256 + 2 * 257) * 4)
  WALLOC(float*, deg_out, (size_t)N * 4)
  WALLOC(int*, rowptr, (size_t)(N + 1) * 4)
  WALLOC(uint32_t*, chunkoff, (size_t)N * 4)
  WALLOC(uint2*, bufD, (size_t)E * 8)
  WALLOC(uint2*, bufS, (size_t)E * 8)
  WALLOC(uint2*, esw, (size_t)E * 8)
  WALLOC(ushort_t*, Wpk, (size_t)180224 * 2)
  WALLOC(uint32_t*, Xp, (size_t)N * D128 * 4)   // hi/lo: x, then h2
  WALLOC(uint32_t*, Xb, (size_t)N * 64 * 4)     // bf16 x
  WALLOC(uint32_t*, A, (size_t)N * 64 * 4)      // bf16 hop-1 result
  WALLOC(uint32_t*, B, (size_t)N * 64 * 4)      // bf16 hop-2 result / h3 plane
  WALLOC(uint32_t*, Hbuf, (size_t)N * 64 * 4)   // bf16 h1/h2 plane
#undef WALLOC

  uint32_t* histD = meta;
  uint32_t* histS = meta + 256;
  uint32_t* curD = meta + 512;
  uint32_t* curS = meta + 768;
  uint32_t* baseD = meta + 1024;
  uint32_t* baseS = meta + 1024 + 257;

  const ushort_t* W0b = Wpk;
  const ushort_t* W1b = Wpk + 49152;
  const ushort_t* W2b = Wpk + 98304;
  const ushort_t* Wp1b = Wpk + 147456;
  const ushort_t* Wp2b = Wpk + 163840;

  const int rb = (N + 3) / 4;
  const int gg = (N + 63) / 64;
  const int nHi = (N + 255) >> 8;

  // ---- sort-based graph build ----
  hipMemsetAsync(meta, 0, 4 * 256 * 4, stream);
  k_hist2<<<128, 256, 0, stream>>>(src, dst, E, histD, histS);
  k_scan2<<<1, 256, 0, stream>>>(histD, histS, curD, baseD, curS, baseS, rowptr, N, E);
  k_part_dst<<<128, 256, 0, stream>>>(src, dst, w, E, curD, bufD);
  k_part_src<<<128, 256, 0, stream>>>(src, w, E, curS, bufS);
  k_sub_dst<<<nHi, 256, 0, stream>>>(bufD, baseD, esw, rowptr, N);
  k_sub_src<<<nHi, 256, 0, stream>>>(bufS, baseS, deg_out, N);
  k_norm<<<rb, 256, 0, stream>>>(deg_out, rowptr, esw, chunkoff, N);

  // ---- pack inputs ----
  k_pack4<<<(N * 32 + 255) / 256, 256, 0, stream>>>(x, Xp, Xb, N * 32);
  k_packW<<<(180224 + 255) / 256, 256, 0, stream>>>(W0, W1, W2, Wp1, Wp2, Wpk);

  // cooperative chunked SpMM launcher
  auto spmm = [&](const uint32_t* Xs, uint32_t* Yd) {
    const uint32_t* xa = Xs;
    uint32_t* ya = Yd;
    const uint2* ea = esw;
    const int* ra = rowptr;
    const uint32_t* ca = chunkoff;
    int na = N;
    void* args[6] = {&xa, &ya, &ea, &ra, &ca, &na};
    hipLaunchCooperativeKernel((void*)k_spmm_coop, dim3(SPMM_BLOCKS), dim3(256),
                               args, 0, stream);
  };

  // ---- layer 1: (Xp, Xb) -> h1 in (Hp hi/lo, Hbuf bf16) ----
  spmm(Xb, A);
  spmm(A, B);
  k_gemm<<<gg, 256, 0, stream>>>(Xp, A, B, W0b, b0, 1, N, Hp, (ushort_t*)Hbuf, nullptr);
  // ---- layer 2: (Hp, Hbuf) -> h2 in (Xp hi/lo, Hbuf bf16) ----
  spmm(Hbuf, A);
  spmm(A, B);
  k_gemm<<<gg, 256, 0, stream>>>(Hp, A, B, W1b, b1, 1, N, Xp, (ushort_t*)Hbuf, nullptr);
  // ---- layer 3: (Xp, Hbuf) -> h3 fp32 in h_fin + bf16 plane in B (alias) ----
  spmm(Hbuf, A);
  spmm(A, B);
  k_gemm<<<gg, 256, 0, stream>>>(Xp, A, B, W2b, b2, 0, N, nullptr, (ushort_t*)B, h_fin);

  // ---- fused predictor over pos+neg (2P pairs) ----
  k_pred<<<(2 * P + 127) / 128, 256, 0, stream>>>(B, pos_src, pos_dst, neg_src, neg_dst,
                                                  Wp1b, Wp2b, bp1, bp2, Wp3, bp3, P, out);
}

// Round 10
// 3921.791 us; speedup vs baseline: 1.0791x; 1.0791x over previous
//
#include <hip/hip_runtime.h>
#include <hip/hip_cooperative_groups.h>
#include <stdint.h>

namespace cg = cooperative_groups;

// ---------------------------------------------------------------------------
// TAGConv(3 layers, K=2) + edge-weight norm + MLP link predictor.
// Round 10: spill-free chunked persistent SpMM. R9's mechanism (src-window
// chunking + grid.sync -> FETCH 205->58MB) was right; launch_bounds(256,8)
// caused total register spill (VGPR=16). Now: 7 rows/wave contiguous,
// metadata reloaded per chunk (only 14 accum floats live), bounds (256,7),
// 1786 blocks <= 1792 co-resident.
// ---------------------------------------------------------------------------

#define D128 128
#define ROWS_PER_WAVE 7

typedef __bf16 v8bf __attribute__((ext_vector_type(8)));
typedef float v4f __attribute__((ext_vector_type(4)));
typedef uint32_t v4u __attribute__((ext_vector_type(4)));
typedef unsigned short ushort_t;

union BFU { v4u u; v8bf b; uint4 q; };

__device__ __forceinline__ uint32_t pack_hl(float f) {
  uint32_t hi = __float_as_uint(f) & 0xffff0000u;
  float lo = f - __uint_as_float(hi);
  return hi | (__float_as_uint(lo) >> 16);
}
__device__ __forceinline__ float unpack_hl(uint32_t p) {
  return __uint_as_float(p & 0xffff0000u) + __uint_as_float(p << 16);
}
__device__ __forceinline__ uint32_t f2bf_rn(float f) {
  uint32_t u = __float_as_uint(f);
  return (u + 0x7fffu + ((u >> 16) & 1u)) >> 16;
}
__device__ __forceinline__ float bflo(uint32_t u) { return __uint_as_float(u << 16); }
__device__ __forceinline__ float bfhi(uint32_t u) { return __uint_as_float(u & 0xffff0000u); }
__device__ __forceinline__ uint32_t bfmul2(uint32_t a, uint32_t b) {
  return f2bf_rn(bflo(a) * bflo(b)) | (f2bf_rn(bfhi(a) * bfhi(b)) << 16);
}

// ---------------- sort-based graph build ------------------------------------

__global__ void k_hist2(const int* __restrict__ src, const int* __restrict__ dst,
                        int E, uint32_t* __restrict__ histD,
                        uint32_t* __restrict__ histS) {
  __shared__ uint32_t hd[256], hs[256];
  int t = threadIdx.x;
  hd[t] = 0; hs[t] = 0;
  __syncthreads();
  for (int e = blockIdx.x * 256 + t; e < E; e += gridDim.x * 256) {
    atomicAdd(&hd[((unsigned)dst[e]) >> 8], 1u);
    atomicAdd(&hs[((unsigned)src[e]) >> 8], 1u);
  }
  __syncthreads();
  if (hd[t]) atomicAdd(&histD[t], hd[t]);
  if (hs[t]) atomicAdd(&histS[t], hs[t]);
}

__global__ void k_scan2(const uint32_t* __restrict__ histD,
                        const uint32_t* __restrict__ histS,
                        uint32_t* __restrict__ curD, uint32_t* __restrict__ baseD,
                        uint32_t* __restrict__ curS, uint32_t* __restrict__ baseS,
                        int* __restrict__ rowptr, int N, int E) {
  __shared__ uint32_t ws[4];
  int t = threadIdx.x;
  int lane = t & 63, wid = t >> 6;
  for (int which = 0; which < 2; ++which) {
    uint32_t v = which ? histS[t] : histD[t];
    uint32_t x = v;
#pragma unroll
    for (int d = 1; d < 64; d <<= 1) {
      uint32_t y = (uint32_t)__shfl_up((int)x, d);
      if (lane >= d) x += y;
    }
    if (lane == 63) ws[wid] = x;
    __syncthreads();
    if (t == 0) {
      uint32_t a = 0;
#pragma unroll
      for (int k = 0; k < 4; ++k) { uint32_t tmp = ws[k]; ws[k] = a; a += tmp; }
    }
    __syncthreads();
    uint32_t ex = x - v + ws[wid];
    if (which == 0) {
      curD[t] = ex; baseD[t] = ex;
      if (t == 0) baseD[256] = (uint32_t)E;
    } else {
      curS[t] = ex; baseS[t] = ex;
      if (t == 0) baseS[256] = (uint32_t)E;
    }
    __syncthreads();
  }
  if (t == 0) rowptr[N] = E;
}

__global__ void k_part_dst(const int* __restrict__ src, const int* __restrict__ dst,
                           const float* __restrict__ w, int E,
                           uint32_t* __restrict__ curD, uint2* __restrict__ bufD) {
  __shared__ uint32_t lh[256], lbase[256];
  int t = threadIdx.x;
  int per = (E + gridDim.x - 1) / gridDim.x;
  int e0 = blockIdx.x * per, e1 = min(e0 + per, E);
  lh[t] = 0;
  __syncthreads();
  for (int e = e0 + t; e < e1; e += 256) atomicAdd(&lh[((unsigned)dst[e]) >> 8], 1u);
  __syncthreads();
  uint32_t c = lh[t];
  lbase[t] = c ? atomicAdd(&curD[t], c) : 0u;
  __syncthreads();
  lh[t] = 0;
  __syncthreads();
  for (int e = e0 + t; e < e1; e += 256) {
    int d = dst[e];
    uint32_t bin = ((unsigned)d) >> 8;
    uint32_t pos = lbase[bin] + atomicAdd(&lh[bin], 1u);
    bufD[pos] = make_uint2((((unsigned)d & 255u) << 16) | (unsigned)src[e],
                           __float_as_uint(w[e]));
  }
}

__global__ void k_part_src(const int* __restrict__ src, const float* __restrict__ w,
                           int E, uint32_t* __restrict__ curS,
                           uint2* __restrict__ bufS) {
  __shared__ uint32_t lh[256], lbase[256];
  int t = threadIdx.x;
  int per = (E + gridDim.x - 1) / gridDim.x;
  int e0 = blockIdx.x * per, e1 = min(e0 + per, E);
  lh[t] = 0;
  __syncthreads();
  for (int e = e0 + t; e < e1; e += 256) atomicAdd(&lh[((unsigned)src[e]) >> 8], 1u);
  __syncthreads();
  uint32_t c = lh[t];
  lbase[t] = c ? atomicAdd(&curS[t], c) : 0u;
  __syncthreads();
  lh[t] = 0;
  __syncthreads();
  for (int e = e0 + t; e < e1; e += 256) {
    int s = src[e];
    uint32_t bin = ((unsigned)s) >> 8;
    uint32_t pos = lbase[bin] + atomicAdd(&lh[bin], 1u);
    bufS[pos] = make_uint2((unsigned)s, __float_as_uint(w[e]));
  }
}

__global__ void k_sub_dst(const uint2* __restrict__ bufD,
                          const uint32_t* __restrict__ baseD,
                          uint2* __restrict__ esw, int* __restrict__ rowptr, int N) {
  __shared__ uint32_t lh[256], cur[256], ws4[4];
  int hb = blockIdx.x, t = threadIdx.x;
  int b = (int)baseD[hb], e = (int)baseD[hb + 1];
  lh[t] = 0;
  __syncthreads();
  for (int i = b + t; i < e; i += 256) atomicAdd(&lh[(bufD[i].x >> 16) & 255u], 1u);
  __syncthreads();
  uint32_t v = lh[t], x = v;
  int lane = t & 63, wid = t >> 6;
#pragma unroll
  for (int d = 1; d < 64; d <<= 1) {
    uint32_t y = (uint32_t)__shfl_up((int)x, d);
    if (lane >= d) x += y;
  }
  if (lane == 63) ws4[wid] = x;
  __syncthreads();
  if (t == 0) {
    uint32_t a = 0;
#pragma unroll
    for (int k = 0; k < 4; ++k) { uint32_t tmp = ws4[k]; ws4[k] = a; a += tmp; }
  }
  __syncthreads();
  uint32_t ex = x - v + ws4[wid];
  cur[t] = ex;
  int d = hb * 256 + t;
  if (d < N) rowptr[d] = b + (int)ex;
  __syncthreads();
  for (int i = b + t; i < e; i += 256) {
    uint2 el = bufD[i];
    uint32_t lo = (el.x >> 16) & 255u;
    uint32_t pos = atomicAdd(&cur[lo], 1u);
    esw[b + pos] = make_uint2(el.x & 0xffffu, el.y);
  }
}

__global__ void k_sub_src(const uint2* __restrict__ bufS,
                          const uint32_t* __restrict__ baseS,
                          float* __restrict__ deg_out, int N) {
  __shared__ float acc[256];
  int hb = blockIdx.x, t = threadIdx.x;
  acc[t] = 0.f;
  __syncthreads();
  int b = (int)baseS[hb], e = (int)baseS[hb + 1];
  for (int i = b + t; i < e; i += 256)
    atomicAdd(&acc[bufS[i].x & 255u], __uint_as_float(bufS[i].y));
  __syncthreads();
  int s = hb * 256 + t;
  if (s < N) deg_out[s] = acc[t];
}

// deg_in + normalize + bitonic sort by src + per-row chunk offsets.
__global__ void k_norm(const float* __restrict__ deg_out, const int* __restrict__ rowptr,
                       uint2* __restrict__ esw, uint32_t* __restrict__ chunkoff,
                       int n) {
  int row = blockIdx.x * 4 + (threadIdx.x >> 6);
  if (row >= n) return;
  int lane = threadIdx.x & 63;
  int b0 = rowptr[row];
  int cnt = rowptr[row + 1] - b0;
  uint32_t q1 = (uint32_t)(n / 4), q2 = (uint32_t)(n / 2), q3 = (uint32_t)((3 * (long long)n) / 4);
  if (cnt <= 64) {
    uint32_t key = 0xffffffffu;
    float val = 0.f;
    if (lane < cnt) {
      uint2 e = esw[b0 + lane];
      key = e.x;
      val = __uint_as_float(e.y);
    }
    float s = val;
#pragma unroll
    for (int d = 32; d; d >>= 1) s += __shfl_xor(s, d);
#pragma unroll
    for (int k = 2; k <= 64; k <<= 1) {
#pragma unroll
      for (int j = k >> 1; j > 0; j >>= 1) {
        uint32_t ok = (uint32_t)__shfl_xor((int)key, j);
        float ov = __shfl_xor(val, j);
        bool asc = ((lane & k) == 0);
        bool lower = ((lane & j) == 0);
        bool take_min = (lower == asc);
        bool sw = take_min ? (ok < key) : (ok > key);
        if (sw) { key = ok; val = ov; }
      }
    }
    uint32_t p1 = (uint32_t)__popcll(__ballot(key < q1));
    uint32_t p2 = (uint32_t)__popcll(__ballot(key < q2));
    uint32_t p3 = (uint32_t)__popcll(__ballot(key < q3));
    if (lane == 0) chunkoff[row] = p1 | (p2 << 8) | (p3 << 16);
    if (lane < cnt) {
      float dout = deg_out[key];
      float nw = val / sqrtf(fmaxf(dout * s, 1e-12f));
      esw[b0 + lane] = make_uint2(key, __float_as_uint(nw));
    }
  } else {
    float s = 0.f;
    int c1 = 0, c2 = 0, c3 = 0;
    for (int i = lane; i < cnt; i += 64) {
      uint2 e = esw[b0 + i];
      s += __uint_as_float(e.y);
      c1 += (e.x < q1); c2 += (e.x < q2); c3 += (e.x < q3);
    }
#pragma unroll
    for (int d = 32; d; d >>= 1) {
      s += __shfl_xor(s, d);
      c1 += __shfl_xor(c1, d);
      c2 += __shfl_xor(c2, d);
      c3 += __shfl_xor(c3, d);
    }
    if (lane == 0) {
      uint32_t p1 = (uint32_t)min(c1, 255), p2 = (uint32_t)min(c2, 255),
               p3 = (uint32_t)min(c3, 255);
      chunkoff[row] = p1 | (p2 << 8) | (p3 << 16);
    }
    for (int i = lane; i < cnt; i += 64) {
      uint2 e = esw[b0 + i];
      float dout = deg_out[e.x];
      float nw = __uint_as_float(e.y) / sqrtf(fmaxf(dout * s, 1e-12f));
      esw[b0 + i] = make_uint2(e.x, __float_as_uint(nw));
    }
  }
}

// ---------------- format conversion ----------------

__global__ void k_pack4(const float* __restrict__ in, uint32_t* __restrict__ Xp,
                        uint32_t* __restrict__ Xb, int n4) {
  int i = blockIdx.x * 256 + threadIdx.x;
  if (i >= n4) return;
  float4 f = ((const float4*)in)[i];
  ((uint4*)Xp)[i] = make_uint4(pack_hl(f.x), pack_hl(f.y), pack_hl(f.z), pack_hl(f.w));
  uint2 b;
  b.x = f2bf_rn(f.x) | (f2bf_rn(f.y) << 16);
  b.y = f2bf_rn(f.z) | (f2bf_rn(f.w) << 16);
  ((uint2*)Xb)[i] = b;
}

__global__ void k_packW(const float* __restrict__ p0, const float* __restrict__ p1,
                        const float* __restrict__ p2, const float* __restrict__ p3,
                        const float* __restrict__ p4, ushort_t* __restrict__ out) {
  int i = blockIdx.x * 256 + threadIdx.x;
  if (i >= 180224) return;
  float f;
  if (i < 49152) f = p0[i];
  else if (i < 98304) f = p1[i - 49152];
  else if (i < 147456) f = p2[i - 98304];
  else if (i < 163840) f = p3[i - 147456];
  else f = p4[i - 163840];
  out[i] = (ushort_t)f2bf_rn(f);
}

// ---------------- chunked persistent SpMM (cooperative, spill-free) ---------
// 7 contiguous rows per wave; only the 14 accumulator floats live across
// chunks — row metadata reloaded from L2 each (chunk,row). grid.sync keeps
// the whole chip in one 3.2MB src window.

__global__ __launch_bounds__(256, 7) void k_spmm_coop(
    const uint32_t* __restrict__ X, uint32_t* __restrict__ Y,
    const uint2* __restrict__ esw, const int* __restrict__ rowptr,
    const uint32_t* __restrict__ chunkoff, int n) {
  cg::grid_group grid = cg::this_grid();
  const int lane = threadIdx.x & 63;
  int gw = (int)(blockIdx.x * 4 + (threadIdx.x >> 6));
  gw = __builtin_amdgcn_readfirstlane(gw);
  const int r0 = gw * ROWS_PER_WAVE;

  float a0[ROWS_PER_WAVE], a1[ROWS_PER_WAVE];
#pragma unroll
  for (int k = 0; k < ROWS_PER_WAVE; ++k) { a0[k] = 0.f; a1[k] = 0.f; }

  for (int c = 0; c < 4; ++c) {
#pragma unroll
    for (int k = 0; k < ROWS_PER_WAVE; ++k) {
      int row = r0 + k;
      if (row < n) {
        int b0 = rowptr[row];
        int cnt = rowptr[row + 1] - b0;
        uint32_t off = chunkoff[row];
        int i0 = (c == 0) ? 0 : (int)((off >> (8 * c - 8)) & 255u);
        int i1 = (c == 3) ? cnt : (int)((off >> (8 * c)) & 255u);
        const uint2* __restrict__ ep = esw + b0;
        int i = i0;
        for (; i + 2 <= i1; i += 2) {
          uint2 e0 = ep[i], e1 = ep[i + 1];
          uint32_t u0 = X[(size_t)e0.x * 64 + lane];
          uint32_t u1 = X[(size_t)e1.x * 64 + lane];
          float w0 = __uint_as_float(e0.y), w1 = __uint_as_float(e1.y);
          a0[k] = fmaf(w0, bflo(u0), a0[k]);
          a1[k] = fmaf(w0, bfhi(u0), a1[k]);
          a0[k] = fmaf(w1, bflo(u1), a0[k]);
          a1[k] = fmaf(w1, bfhi(u1), a1[k]);
        }
        if (i < i1) {
          uint2 e = ep[i];
          uint32_t u = X[(size_t)e.x * 64 + lane];
          float w0 = __uint_as_float(e.y);
          a0[k] = fmaf(w0, bflo(u), a0[k]);
          a1[k] = fmaf(w0, bfhi(u), a1[k]);
        }
      }
    }
    if (c < 3) grid.sync();
  }

#pragma unroll
  for (int k = 0; k < ROWS_PER_WAVE; ++k) {
    int row = r0 + k;
    if (row < n)
      Y[(size_t)row * 64 + lane] = f2bf_rn(a0[k]) | (f2bf_rn(a1[k]) << 16);
  }
}

// ---------------- MFMA GEMM --------------------------------------------------

__device__ __forceinline__ void build_frags_v(uint4 q0, uint4 q1, v8bf& hi, v8bf& lo) {
  BFU uh, ul;
  uh.u[0] = (q0.x >> 16) | (q0.y & 0xffff0000u);
  uh.u[1] = (q0.z >> 16) | (q0.w & 0xffff0000u);
  uh.u[2] = (q1.x >> 16) | (q1.y & 0xffff0000u);
  uh.u[3] = (q1.z >> 16) | (q1.w & 0xffff0000u);
  ul.u[0] = (q0.x & 0xffffu) | (q0.y << 16);
  ul.u[1] = (q0.z & 0xffffu) | (q0.w << 16);
  ul.u[2] = (q1.x & 0xffffu) | (q1.y << 16);
  ul.u[3] = (q1.z & 0xffffu) | (q1.w << 16);
  hi = uh.b;
  lo = ul.b;
}

__global__ __launch_bounds__(256) void k_gemm(
    const uint32_t* __restrict__ F0hl, const uint32_t* __restrict__ F1b,
    const uint32_t* __restrict__ F2b, const ushort_t* __restrict__ Wb,
    const float* __restrict__ bias, int relu, int M,
    uint32_t* __restrict__ outp, ushort_t* __restrict__ outh,
    float* __restrict__ outf) {
  __shared__ ushort_t Wl[128 * 128];  // 32 KB swizzled
  const int t = threadIdx.x;
  const int lane = t & 63;
  const int wave = t >> 6;
  const int wr = wave >> 1, wc = wave & 1;
  const int row0 = blockIdx.x * 64;
  const int l15 = lane & 15;
  const int kg = lane >> 4;

  int arow[2];
#pragma unroll
  for (int mr = 0; mr < 2; ++mr)
    arow[mr] = min(row0 + wr * 32 + mr * 16 + l15, M - 1);
  int wcol[4];
  float bv[4];
#pragma unroll
  for (int nr = 0; nr < 4; ++nr) {
    wcol[nr] = wc * 64 + nr * 16 + l15;
    bv[nr] = bias[wcol[nr]];
  }

  const uint32_t* __restrict__ F0r0 = F0hl + (size_t)arow[0] * D128 + kg * 8;
  const uint32_t* __restrict__ F0r1 = F0hl + (size_t)arow[1] * D128 + kg * 8;
  const uint32_t* __restrict__ F1r0 = F1b + (size_t)arow[0] * 64 + kg * 4;
  const uint32_t* __restrict__ F1r1 = F1b + (size_t)arow[1] * 64 + kg * 4;
  const uint32_t* __restrict__ F2r0 = F2b + (size_t)arow[0] * 64 + kg * 4;
  const uint32_t* __restrict__ F2r1 = F2b + (size_t)arow[1] * 64 + kg * 4;

  v4f acc[2][4];
#pragma unroll
  for (int mr = 0; mr < 2; ++mr)
#pragma unroll
    for (int nr = 0; nr < 4; ++nr) acc[mr][nr] = (v4f){0.f, 0.f, 0.f, 0.f};

  const int sc = t >> 1;
  const int sh = t & 1;
  const ushort_t* gpW = Wb + (size_t)sc * 384 + sh * 64;
  char* WlBase = (char*)Wl + sc * 256;

  // ---------------- seg0 (hi/lo plane, 2 MFMA per frag) ----------------
  uint4 f0[4][2][2];
#pragma unroll
  for (int kc = 0; kc < 2; ++kc) {
    f0[kc][0][0] = *(const uint4*)(F0r0 + kc * 32);
    f0[kc][0][1] = *(const uint4*)(F0r0 + kc * 32 + 4);
    f0[kc][1][0] = *(const uint4*)(F0r1 + kc * 32);
    f0[kc][1][1] = *(const uint4*)(F0r1 + kc * 32 + 4);
  }
  __syncthreads();
  {
    const ushort_t* gp = gpW;
#pragma unroll
    for (int gi = 0; gi < 8; ++gi) {
      int gg = sh * 8 + gi;
      uint4 v = *(const uint4*)(gp + gi * 8);
      *(uint4*)(WlBase + ((gg ^ (sc & 7)) * 16)) = v;
    }
  }
  __syncthreads();
#pragma unroll
  for (int kc = 0; kc < 4; ++kc) {
    if (kc < 2) {
      f0[kc + 2][0][0] = *(const uint4*)(F0r0 + (kc + 2) * 32);
      f0[kc + 2][0][1] = *(const uint4*)(F0r0 + (kc + 2) * 32 + 4);
      f0[kc + 2][1][0] = *(const uint4*)(F0r1 + (kc + 2) * 32);
      f0[kc + 2][1][1] = *(const uint4*)(F0r1 + (kc + 2) * 32 + 4);
    }
    v8bf ah[2], al[2];
#pragma unroll
    for (int mr = 0; mr < 2; ++mr)
      build_frags_v(f0[kc][mr][0], f0[kc][mr][1], ah[mr], al[mr]);
#pragma unroll
    for (int nr = 0; nr < 4; ++nr) {
      int col = wcol[nr];
      int g = (kc << 2) + kg;
      v8bf bf = *(const v8bf*)((const char*)Wl + col * 256 + ((g ^ (col & 7)) * 16));
#pragma unroll
      for (int mr = 0; mr < 2; ++mr) {
        acc[mr][nr] = __builtin_amdgcn_mfma_f32_16x16x32_bf16(ah[mr], bf, acc[mr][nr], 0, 0, 0);
        acc[mr][nr] = __builtin_amdgcn_mfma_f32_16x16x32_bf16(al[mr], bf, acc[mr][nr], 0, 0, 0);
      }
    }
  }

  // ---------------- seg1, seg2 (bf16 planes, full preload) ----------------
#pragma unroll
  for (int seg = 1; seg < 3; ++seg) {
    const uint32_t* __restrict__ Fr0 = (seg == 1) ? F1r0 : F2r0;
    const uint32_t* __restrict__ Fr1 = (seg == 1) ? F1r1 : F2r1;
    uint4 fb[4][2];
#pragma unroll
    for (int kc = 0; kc < 4; ++kc) {
      fb[kc][0] = *(const uint4*)(Fr0 + kc * 16);
      fb[kc][1] = *(const uint4*)(Fr1 + kc * 16);
    }
    __syncthreads();
    {
      const ushort_t* gp = gpW + seg * 128;
#pragma unroll
      for (int gi = 0; gi < 8; ++gi) {
        int gg = sh * 8 + gi;
        uint4 v = *(const uint4*)(gp + gi * 8);
        *(uint4*)(WlBase + ((gg ^ (sc & 7)) * 16)) = v;
      }
    }
    __syncthreads();
#pragma unroll
    for (int kc = 0; kc < 4; ++kc) {
      v8bf af[2];
      {
        BFU u0, u1;
        u0.q = fb[kc][0];
        u1.q = fb[kc][1];
        af[0] = u0.b;
        af[1] = u1.b;
      }
#pragma unroll
      for (int nr = 0; nr < 4; ++nr) {
        int col = wcol[nr];
        int g = (kc << 2) + kg;
        v8bf bf = *(const v8bf*)((const char*)Wl + col * 256 + ((g ^ (col & 7)) * 16));
#pragma unroll
        for (int mr = 0; mr < 2; ++mr)
          acc[mr][nr] = __builtin_amdgcn_mfma_f32_16x16x32_bf16(af[mr], bf, acc[mr][nr], 0, 0, 0);
      }
    }
  }

  __syncthreads();  // all reads done before (possibly aliased) epilogue writes

#pragma unroll
  for (int mr = 0; mr < 2; ++mr) {
#pragma unroll
    for (int nr = 0; nr < 4; ++nr) {
      v4f a = acc[mr][nr];
#pragma unroll
      for (int r = 0; r < 4; ++r) {
        int row = row0 + wr * 32 + mr * 16 + kg * 4 + r;
        if (row < M) {
          float v = a[r] + bv[nr];
          if (relu) v = fmaxf(v, 0.f);
          size_t o = (size_t)row * D128 + wcol[nr];
          if (outp) outp[o] = pack_hl(v);
          if (outh) outh[o] = (ushort_t)f2bf_rn(v);
          if (outf) outf[o] = v;
        }
      }
    }
  }
}

// ---------------- fused predictor (128 pairs/block, 2 chunks) ----------------

__global__ __launch_bounds__(256) void k_pred(
    const uint32_t* __restrict__ Hb, const int* __restrict__ pos_src,
    const int* __restrict__ pos_dst, const int* __restrict__ neg_src,
    const int* __restrict__ neg_dst, const ushort_t* __restrict__ W1,
    const ushort_t* __restrict__ W2, const float* __restrict__ b1,
    const float* __restrict__ b2, const float* __restrict__ w3,
    const float* __restrict__ b3, int P, float* __restrict__ out) {
  __shared__ ushort_t Wl[128 * 128];
  const int t = threadIdx.x;
  const int lane = t & 63;
  const int wave = t >> 6;
  const int l15 = lane & 15;
  const int kg = lane >> 4;
  const int P2 = 2 * P;

  const int qA = blockIdx.x * 128 + wave * 16 + l15;
  const int qB = qA + 64;
  const bool vA = qA < P2, vB = qB < P2;
  const int qcA = vA ? qA : (P2 - 1);
  const int qcB = vB ? qB : (P2 - 1);
  const int iaA = (qcA < P) ? pos_src[qcA] : neg_src[qcA - P];
  const int ibA = (qcA < P) ? pos_dst[qcA] : neg_dst[qcA - P];
  const int iaB = (qcB < P) ? pos_src[qcB] : neg_src[qcB - P];
  const int ibB = (qcB < P) ? pos_dst[qcB] : neg_dst[qcB - P];

  const int sc = t >> 1;
  const int sh = t & 1;

  // ---- stage W1 ----
  {
    const ushort_t* gp = W1 + sc * 128 + sh * 64;
#pragma unroll
    for (int gi = 0; gi < 8; ++gi) {
      int gg = sh * 8 + gi;
      uint4 v = *(const uint4*)(gp + gi * 8);
      *(uint4*)((char*)Wl + sc * 256 + ((gg ^ (sc & 7)) * 16)) = v;
    }
  }

  // ---- gather both chunks (32 independent 16B loads in flight) ----
  uint4 gaA[4], gbA[4], gaB[4], gbB[4];
#pragma unroll
  for (int kc = 0; kc < 4; ++kc) {
    gaA[kc] = *(const uint4*)(Hb + (size_t)iaA * 64 + kc * 16 + kg * 4);
    gbA[kc] = *(const uint4*)(Hb + (size_t)ibA * 64 + kc * 16 + kg * 4);
    gaB[kc] = *(const uint4*)(Hb + (size_t)iaB * 64 + kc * 16 + kg * 4);
    gbB[kc] = *(const uint4*)(Hb + (size_t)ibB * 64 + kc * 16 + kg * 4);
  }
  v8bf zfA[4], zfB[4];
#pragma unroll
  for (int kc = 0; kc < 4; ++kc) {
    BFU zA, zB;
    zA.u[0] = bfmul2(gaA[kc].x, gbA[kc].x);
    zA.u[1] = bfmul2(gaA[kc].y, gbA[kc].y);
    zA.u[2] = bfmul2(gaA[kc].z, gbA[kc].z);
    zA.u[3] = bfmul2(gaA[kc].w, gbA[kc].w);
    zB.u[0] = bfmul2(gaB[kc].x, gbB[kc].x);
    zB.u[1] = bfmul2(gaB[kc].y, gbB[kc].y);
    zB.u[2] = bfmul2(gaB[kc].z, gbB[kc].z);
    zB.u[3] = bfmul2(gaB[kc].w, gbB[kc].w);
    zfA[kc] = zA.b;
    zfB[kc] = zB.b;
  }
  __syncthreads();

  // ---- layer 1, chunk A then chunk B ----
  uint32_t pkA[8][2], pkB[8][2];
  {
    v4f acc1[8];
#pragma unroll
    for (int nr = 0; nr < 8; ++nr) acc1[nr] = (v4f){0.f, 0.f, 0.f, 0.f};
#pragma unroll
    for (int kc = 0; kc < 4; ++kc) {
#pragma unroll
      for (int nr = 0; nr < 8; ++nr) {
        int c = nr * 16 + l15;
        int g = 4 * kc + kg;
        v8bf wf = *(const v8bf*)((const char*)Wl + c * 256 + ((g ^ (c & 7)) * 16));
        acc1[nr] = __builtin_amdgcn_mfma_f32_16x16x32_bf16(wf, zfA[kc], acc1[nr], 0, 0, 0);
      }
    }
#pragma unroll
    for (int nr = 0; nr < 8; ++nr) {
      float v0 = fmaxf(acc1[nr][0] + b1[nr * 16 + kg * 4 + 0], 0.f);
      float v1 = fmaxf(acc1[nr][1] + b1[nr * 16 + kg * 4 + 1], 0.f);
      float v2 = fmaxf(acc1[nr][2] + b1[nr * 16 + kg * 4 + 2], 0.f);
      float v3 = fmaxf(acc1[nr][3] + b1[nr * 16 + kg * 4 + 3], 0.f);
      pkA[nr][0] = f2bf_rn(v0) | (f2bf_rn(v1) << 16);
      pkA[nr][1] = f2bf_rn(v2) | (f2bf_rn(v3) << 16);
    }
  }
  {
    v4f acc1[8];
#pragma unroll
    for (int nr = 0; nr < 8; ++nr) acc1[nr] = (v4f){0.f, 0.f, 0.f, 0.f};
#pragma unroll
    for (int kc = 0; kc < 4; ++kc) {
#pragma unroll
      for (int nr = 0; nr < 8; ++nr) {
        int c = nr * 16 + l15;
        int g = 4 * kc + kg;
        v8bf wf = *(const v8bf*)((const char*)Wl + c * 256 + ((g ^ (c & 7)) * 16));
        acc1[nr] = __builtin_amdgcn_mfma_f32_16x16x32_bf16(wf, zfB[kc], acc1[nr], 0, 0, 0);
      }
    }
#pragma unroll
    for (int nr = 0; nr < 8; ++nr) {
      float v0 = fmaxf(acc1[nr][0] + b1[nr * 16 + kg * 4 + 0], 0.f);
      float v1 = fmaxf(acc1[nr][1] + b1[nr * 16 + kg * 4 + 1], 0.f);
      float v2 = fmaxf(acc1[nr][2] + b1[nr * 16 + kg * 4 + 2], 0.f);
      float v3 = fmaxf(acc1[nr][3] + b1[nr * 16 + kg * 4 + 3], 0.f);
      pkB[nr][0] = f2bf_rn(v0) | (f2bf_rn(v1) << 16);
      pkB[nr][1] = f2bf_rn(v2) | (f2bf_rn(v3) << 16);
    }
  }

  // ---- restage W2 ----
  __syncthreads();
  {
    const ushort_t* gp = W2 + sc * 128 + sh * 64;
#pragma unroll
    for (int gi = 0; gi < 8; ++gi) {
      int gg = sh * 8 + gi;
      uint4 v = *(const uint4*)(gp + gi * 8);
      *(uint4*)((char*)Wl + sc * 256 + ((gg ^ (sc & 7)) * 16)) = v;
    }
  }
  __syncthreads();

  // ---- layer 2 + dot, chunk A then chunk B ----
#pragma unroll
  for (int chunk = 0; chunk < 2; ++chunk) {
    v4f acc2[8];
#pragma unroll
    for (int nr = 0; nr < 8; ++nr) acc2[nr] = (v4f){0.f, 0.f, 0.f, 0.f};
#pragma unroll
    for (int kc = 0; kc < 4; ++kc) {
      BFU y;
#pragma unroll
      for (int d = 0; d < 4; ++d) {
        int srcLane = l15 + 16 * ((kg & 1) * 2 + (d >> 1));
        uint32_t w0, w1;
        if (chunk == 0) {
          w0 = (uint32_t)__shfl((int)pkA[2 * kc][d & 1], srcLane);
          w1 = (uint32_t)__shfl((int)pkA[2 * kc + 1][d & 1], srcLane);
        } else {
          w0 = (uint32_t)__shfl((int)pkB[2 * kc][d & 1], srcLane);
          w1 = (uint32_t)__shfl((int)pkB[2 * kc + 1][d & 1], srcLane);
        }
        y.u[d] = (kg & 2) ? w1 : w0;
      }
#pragma unroll
      for (int nr = 0; nr < 8; ++nr) {
        int c = nr * 16 + l15;
        int g = 4 * kc + kg;
        v8bf wf = *(const v8bf*)((const char*)Wl + c * 256 + ((g ^ (c & 7)) * 16));
        acc2[nr] = __builtin_amdgcn_mfma_f32_16x16x32_bf16(wf, y.b, acc2[nr], 0, 0, 0);
      }
    }
    float s = 0.f;
#pragma unroll
    for (int nr = 0; nr < 8; ++nr) {
#pragma unroll
      for (int r = 0; r < 4; ++r) {
        int c = nr * 16 + kg * 4 + r;
        s += fmaxf(acc2[nr][r] + b2[c], 0.f) * w3[c];
      }
    }
    s += __shfl_xor(s, 16);
    s += __shfl_xor(s, 32);
    if (chunk == 0) {
      if (vA && kg == 0) out[qA] = s + b3[0];
    } else {
      if (vB && kg == 0) out[qB] = s + b3[0];
    }
  }
}

// ---------------- launch ----------------

extern "C" void kernel_launch(void* const* d_in, const int* in_sizes, int n_in,
                              void* d_out, int out_size, void* d_ws, size_t ws_size,
                              hipStream_t stream) {
  const float* x = (const float*)d_in[0];
  const float* w = (const float*)d_in[1];
  const int* src = (const int*)d_in[2];
  const int* dst = (const int*)d_in[3];
  const int* pos_src = (const int*)d_in[4];
  const int* pos_dst = (const int*)d_in[5];
  const int* neg_src = (const int*)d_in[6];
  const int* neg_dst = (const int*)d_in[7];
  const float* W0 = (const float*)d_in[8];
  const float* b0 = (const float*)d_in[9];
  const float* W1 = (const float*)d_in[10];
  const float* b1 = (const float*)d_in[11];
  const float* W2 = (const float*)d_in[12];
  const float* b2 = (const float*)d_in[13];
  const float* Wp1 = (const float*)d_in[14];
  const float* bp1 = (const float*)d_in[15];
  const float* Wp2 = (const float*)d_in[16];
  const float* bp2 = (const float*)d_in[17];
  const float* Wp3 = (const float*)d_in[18];
  const float* bp3 = (const float*)d_in[19];

  const int N = in_sizes[0] / D128;
  const int E = in_sizes[1];
  const int P = in_sizes[4];

  float* out = (float*)d_out;
  float* h_fin = out + 2 * (size_t)P;   // [N,128] fp32 final h (d_out)
  uint32_t* Hp = (uint32_t*)h_fin;      // reused as hi/lo h1 scratch

  char* p = (char*)d_ws;
#define WALLOC(T, name, bytes) \
  T name = (T)p;               \
  p += (((size_t)(bytes) + 255) & ~(size_t)255);
  WALLOC(uint32_t*, meta, (size_t)(4 * 256 + 2 * 257) * 4)
  WALLOC(float*, deg_out, (size_t)N * 4)
  WALLOC(int*, rowptr, (size_t)(N + 1) * 4)
  WALLOC(uint32_t*, chunkoff, (size_t)N * 4)
  WALLOC(uint2*, bufD, (size_t)E * 8)
  WALLOC(uint2*, bufS, (size_t)E * 8)
  WALLOC(uint2*, esw, (size_t)E * 8)
  WALLOC(ushort_t*, Wpk, (size_t)180224 * 2)
  WALLOC(uint32_t*, Xp, (size_t)N * D128 * 4)   // hi/lo: x, then h2
  WALLOC(uint32_t*, Xb, (size_t)N * 64 * 4)     // bf16 x
  WALLOC(uint32_t*, A, (size_t)N * 64 * 4)      // bf16 hop-1 result
  WALLOC(uint32_t*, B, (size_t)N * 64 * 4)      // bf16 hop-2 result / h3 plane
  WALLOC(uint32_t*, Hbuf, (size_t)N * 64 * 4)   // bf16 h1/h2 plane
#undef WALLOC

  uint32_t* histD = meta;
  uint32_t* histS = meta + 256;
  uint32_t* curD = meta + 512;
  uint32_t* curS = meta + 768;
  uint32_t* baseD = meta + 1024;
  uint32_t* baseS = meta + 1024 + 257;

  const ushort_t* W0b = Wpk;
  const ushort_t* W1b = Wpk + 49152;
  const ushort_t* W2b = Wpk + 98304;
  const ushort_t* Wp1b = Wpk + 147456;
  const ushort_t* Wp2b = Wpk + 163840;

  const int rb = (N + 3) / 4;
  const int gg = (N + 63) / 64;
  const int nHi = (N + 255) >> 8;
  const int spmm_blocks = (N + ROWS_PER_WAVE * 4 - 1) / (ROWS_PER_WAVE * 4);

  // ---- sort-based graph build ----
  hipMemsetAsync(meta, 0, 4 * 256 * 4, stream);
  k_hist2<<<128, 256, 0, stream>>>(src, dst, E, histD, histS);
  k_scan2<<<1, 256, 0, stream>>>(histD, histS, curD, baseD, curS, baseS, rowptr, N, E);
  k_part_dst<<<128, 256, 0, stream>>>(src, dst, w, E, curD, bufD);
  k_part_src<<<128, 256, 0, stream>>>(src, w, E, curS, bufS);
  k_sub_dst<<<nHi, 256, 0, stream>>>(bufD, baseD, esw, rowptr, N);
  k_sub_src<<<nHi, 256, 0, stream>>>(bufS, baseS, deg_out, N);
  k_norm<<<rb, 256, 0, stream>>>(deg_out, rowptr, esw, chunkoff, N);

  // ---- pack inputs ----
  k_pack4<<<(N * 32 + 255) / 256, 256, 0, stream>>>(x, Xp, Xb, N * 32);
  k_packW<<<(180224 + 255) / 256, 256, 0, stream>>>(W0, W1, W2, Wp1, Wp2, Wpk);

  // cooperative chunked SpMM launcher
  auto spmm = [&](const uint32_t* Xs, uint32_t* Yd) {
    const uint32_t* xa = Xs;
    uint32_t* ya = Yd;
    const uint2* ea = esw;
    const int* ra = rowptr;
    const uint32_t* ca = chunkoff;
    int na = N;
    void* args[6] = {&xa, &ya, &ea, &ra, &ca, &na};
    hipLaunchCooperativeKernel((void*)k_spmm_coop, dim3(spmm_blocks), dim3(256),
                               args, 0, stream);
  };

  // ---- layer 1: (Xp, Xb) -> h1 in (Hp hi/lo, Hbuf bf16) ----
  spmm(Xb, A);
  spmm(A, B);
  k_gemm<<<gg, 256, 0, stream>>>(Xp, A, B, W0b, b0, 1, N, Hp, (ushort_t*)Hbuf, nullptr);
  // ---- layer 2: (Hp, Hbuf) -> h2 in (Xp hi/lo, Hbuf bf16) ----
  spmm(Hbuf, A);
  spmm(A, B);
  k_gemm<<<gg, 256, 0, stream>>>(Hp, A, B, W1b, b1, 1, N, Xp, (ushort_t*)Hbuf, nullptr);
  // ---- layer 3: (Xp, Hbuf) -> h3 fp32 in h_fin + bf16 plane in B (alias) ----
  spmm(Hbuf, A);
  spmm(A, B);
  k_gemm<<<gg, 256, 0, stream>>>(Xp, A, B, W2b, b2, 0, N, nullptr, (ushort_t*)B, h_fin);

  // ---- fused predictor over pos+neg (2P pairs) ----
  k_pred<<<(2 * P + 127) / 128, 256, 0, stream>>>(B, pos_src, pos_dst, neg_src, neg_dst,
                                                  Wp1b, Wp2b, bp1, bp2, Wp3, bp3, P, out);
}

// Round 11
// 542.040 us; speedup vs baseline: 7.8078x; 7.2352x over previous
//
#include <hip/hip_runtime.h>
#include <stdint.h>

// ---------------------------------------------------------------------------
// TAGConv(3 layers, K=2) + edge-weight norm + MLP link predictor.
// Round 11: chunked SpMM WITHOUT cooperative groups. R9/R10 showed (a) the
// src-window chunking kills over-fetch (FETCH 205->57MB), (b) cg grid.sync's
// external call spills all registers (VGPR=12/16, 600+us). Chunk phases are a
// locality heuristic only -> plain launch, no sync, normal codegen: 8 rows
// per wave, fp32 accums in registers, per-chunk metadata reload.
// ---------------------------------------------------------------------------

#define D128 128
#define RPW 8  // rows per wave in k_spmm_chunk

typedef __bf16 v8bf __attribute__((ext_vector_type(8)));
typedef float v4f __attribute__((ext_vector_type(4)));
typedef uint32_t v4u __attribute__((ext_vector_type(4)));
typedef unsigned short ushort_t;

union BFU { v4u u; v8bf b; uint4 q; };

__device__ __forceinline__ uint32_t pack_hl(float f) {
  uint32_t hi = __float_as_uint(f) & 0xffff0000u;
  float lo = f - __uint_as_float(hi);
  return hi | (__float_as_uint(lo) >> 16);
}
__device__ __forceinline__ float unpack_hl(uint32_t p) {
  return __uint_as_float(p & 0xffff0000u) + __uint_as_float(p << 16);
}
__device__ __forceinline__ uint32_t f2bf_rn(float f) {
  uint32_t u = __float_as_uint(f);
  return (u + 0x7fffu + ((u >> 16) & 1u)) >> 16;
}
__device__ __forceinline__ float bflo(uint32_t u) { return __uint_as_float(u << 16); }
__device__ __forceinline__ float bfhi(uint32_t u) { return __uint_as_float(u & 0xffff0000u); }
__device__ __forceinline__ uint32_t bfmul2(uint32_t a, uint32_t b) {
  return f2bf_rn(bflo(a) * bflo(b)) | (f2bf_rn(bfhi(a) * bfhi(b)) << 16);
}

// ---------------- sort-based graph build ------------------------------------

__global__ void k_hist2(const int* __restrict__ src, const int* __restrict__ dst,
                        int E, uint32_t* __restrict__ histD,
                        uint32_t* __restrict__ histS) {
  __shared__ uint32_t hd[256], hs[256];
  int t = threadIdx.x;
  hd[t] = 0; hs[t] = 0;
  __syncthreads();
  for (int e = blockIdx.x * 256 + t; e < E; e += gridDim.x * 256) {
    atomicAdd(&hd[((unsigned)dst[e]) >> 8], 1u);
    atomicAdd(&hs[((unsigned)src[e]) >> 8], 1u);
  }
  __syncthreads();
  if (hd[t]) atomicAdd(&histD[t], hd[t]);
  if (hs[t]) atomicAdd(&histS[t], hs[t]);
}

__global__ void k_scan2(const uint32_t* __restrict__ histD,
                        const uint32_t* __restrict__ histS,
                        uint32_t* __restrict__ curD, uint32_t* __restrict__ baseD,
                        uint32_t* __restrict__ curS, uint32_t* __restrict__ baseS,
                        int* __restrict__ rowptr, int N, int E) {
  __shared__ uint32_t ws[4];
  int t = threadIdx.x;
  int lane = t & 63, wid = t >> 6;
  for (int which = 0; which < 2; ++which) {
    uint32_t v = which ? histS[t] : histD[t];
    uint32_t x = v;
#pragma unroll
    for (int d = 1; d < 64; d <<= 1) {
      uint32_t y = (uint32_t)__shfl_up((int)x, d);
      if (lane >= d) x += y;
    }
    if (lane == 63) ws[wid] = x;
    __syncthreads();
    if (t == 0) {
      uint32_t a = 0;
#pragma unroll
      for (int k = 0; k < 4; ++k) { uint32_t tmp = ws[k]; ws[k] = a; a += tmp; }
    }
    __syncthreads();
    uint32_t ex = x - v + ws[wid];
    if (which == 0) {
      curD[t] = ex; baseD[t] = ex;
      if (t == 0) baseD[256] = (uint32_t)E;
    } else {
      curS[t] = ex; baseS[t] = ex;
      if (t == 0) baseS[256] = (uint32_t)E;
    }
    __syncthreads();
  }
  if (t == 0) rowptr[N] = E;
}

__global__ void k_part_dst(const int* __restrict__ src, const int* __restrict__ dst,
                           const float* __restrict__ w, int E,
                           uint32_t* __restrict__ curD, uint2* __restrict__ bufD) {
  __shared__ uint32_t lh[256], lbase[256];
  int t = threadIdx.x;
  int per = (E + gridDim.x - 1) / gridDim.x;
  int e0 = blockIdx.x * per, e1 = min(e0 + per, E);
  lh[t] = 0;
  __syncthreads();
  for (int e = e0 + t; e < e1; e += 256) atomicAdd(&lh[((unsigned)dst[e]) >> 8], 1u);
  __syncthreads();
  uint32_t c = lh[t];
  lbase[t] = c ? atomicAdd(&curD[t], c) : 0u;
  __syncthreads();
  lh[t] = 0;
  __syncthreads();
  for (int e = e0 + t; e < e1; e += 256) {
    int d = dst[e];
    uint32_t bin = ((unsigned)d) >> 8;
    uint32_t pos = lbase[bin] + atomicAdd(&lh[bin], 1u);
    bufD[pos] = make_uint2((((unsigned)d & 255u) << 16) | (unsigned)src[e],
                           __float_as_uint(w[e]));
  }
}

__global__ void k_part_src(const int* __restrict__ src, const float* __restrict__ w,
                           int E, uint32_t* __restrict__ curS,
                           uint2* __restrict__ bufS) {
  __shared__ uint32_t lh[256], lbase[256];
  int t = threadIdx.x;
  int per = (E + gridDim.x - 1) / gridDim.x;
  int e0 = blockIdx.x * per, e1 = min(e0 + per, E);
  lh[t] = 0;
  __syncthreads();
  for (int e = e0 + t; e < e1; e += 256) atomicAdd(&lh[((unsigned)src[e]) >> 8], 1u);
  __syncthreads();
  uint32_t c = lh[t];
  lbase[t] = c ? atomicAdd(&curS[t], c) : 0u;
  __syncthreads();
  lh[t] = 0;
  __syncthreads();
  for (int e = e0 + t; e < e1; e += 256) {
    int s = src[e];
    uint32_t bin = ((unsigned)s) >> 8;
    uint32_t pos = lbase[bin] + atomicAdd(&lh[bin], 1u);
    bufS[pos] = make_uint2((unsigned)s, __float_as_uint(w[e]));
  }
}

__global__ void k_sub_dst(const uint2* __restrict__ bufD,
                          const uint32_t* __restrict__ baseD,
                          uint2* __restrict__ esw, int* __restrict__ rowptr, int N) {
  __shared__ uint32_t lh[256], cur[256], ws4[4];
  int hb = blockIdx.x, t = threadIdx.x;
  int b = (int)baseD[hb], e = (int)baseD[hb + 1];
  lh[t] = 0;
  __syncthreads();
  for (int i = b + t; i < e; i += 256) atomicAdd(&lh[(bufD[i].x >> 16) & 255u], 1u);
  __syncthreads();
  uint32_t v = lh[t], x = v;
  int lane = t & 63, wid = t >> 6;
#pragma unroll
  for (int d = 1; d < 64; d <<= 1) {
    uint32_t y = (uint32_t)__shfl_up((int)x, d);
    if (lane >= d) x += y;
  }
  if (lane == 63) ws4[wid] = x;
  __syncthreads();
  if (t == 0) {
    uint32_t a = 0;
#pragma unroll
    for (int k = 0; k < 4; ++k) { uint32_t tmp = ws4[k]; ws4[k] = a; a += tmp; }
  }
  __syncthreads();
  uint32_t ex = x - v + ws4[wid];
  cur[t] = ex;
  int d = hb * 256 + t;
  if (d < N) rowptr[d] = b + (int)ex;
  __syncthreads();
  for (int i = b + t; i < e; i += 256) {
    uint2 el = bufD[i];
    uint32_t lo = (el.x >> 16) & 255u;
    uint32_t pos = atomicAdd(&cur[lo], 1u);
    esw[b + pos] = make_uint2(el.x & 0xffffu, el.y);
  }
}

__global__ void k_sub_src(const uint2* __restrict__ bufS,
                          const uint32_t* __restrict__ baseS,
                          float* __restrict__ deg_out, int N) {
  __shared__ float acc[256];
  int hb = blockIdx.x, t = threadIdx.x;
  acc[t] = 0.f;
  __syncthreads();
  int b = (int)baseS[hb], e = (int)baseS[hb + 1];
  for (int i = b + t; i < e; i += 256)
    atomicAdd(&acc[bufS[i].x & 255u], __uint_as_float(bufS[i].y));
  __syncthreads();
  int s = hb * 256 + t;
  if (s < N) deg_out[s] = acc[t];
}

// deg_in + normalize + bitonic sort by src + per-row chunk offsets.
__global__ void k_norm(const float* __restrict__ deg_out, const int* __restrict__ rowptr,
                       uint2* __restrict__ esw, uint32_t* __restrict__ chunkoff,
                       int n) {
  int row = blockIdx.x * 4 + (threadIdx.x >> 6);
  if (row >= n) return;
  int lane = threadIdx.x & 63;
  int b0 = rowptr[row];
  int cnt = rowptr[row + 1] - b0;
  uint32_t q1 = (uint32_t)(n / 4), q2 = (uint32_t)(n / 2), q3 = (uint32_t)((3 * (long long)n) / 4);
  if (cnt <= 64) {
    uint32_t key = 0xffffffffu;
    float val = 0.f;
    if (lane < cnt) {
      uint2 e = esw[b0 + lane];
      key = e.x;
      val = __uint_as_float(e.y);
    }
    float s = val;
#pragma unroll
    for (int d = 32; d; d >>= 1) s += __shfl_xor(s, d);
#pragma unroll
    for (int k = 2; k <= 64; k <<= 1) {
#pragma unroll
      for (int j = k >> 1; j > 0; j >>= 1) {
        uint32_t ok = (uint32_t)__shfl_xor((int)key, j);
        float ov = __shfl_xor(val, j);
        bool asc = ((lane & k) == 0);
        bool lower = ((lane & j) == 0);
        bool take_min = (lower == asc);
        bool sw = take_min ? (ok < key) : (ok > key);
        if (sw) { key = ok; val = ov; }
      }
    }
    uint32_t p1 = (uint32_t)__popcll(__ballot(key < q1));
    uint32_t p2 = (uint32_t)__popcll(__ballot(key < q2));
    uint32_t p3 = (uint32_t)__popcll(__ballot(key < q3));
    if (lane == 0) chunkoff[row] = p1 | (p2 << 8) | (p3 << 16);
    if (lane < cnt) {
      float dout = deg_out[key];
      float nw = val / sqrtf(fmaxf(dout * s, 1e-12f));
      esw[b0 + lane] = make_uint2(key, __float_as_uint(nw));
    }
  } else {
    float s = 0.f;
    int c1 = 0, c2 = 0, c3 = 0;
    for (int i = lane; i < cnt; i += 64) {
      uint2 e = esw[b0 + i];
      s += __uint_as_float(e.y);
      c1 += (e.x < q1); c2 += (e.x < q2); c3 += (e.x < q3);
    }
#pragma unroll
    for (int d = 32; d; d >>= 1) {
      s += __shfl_xor(s, d);
      c1 += __shfl_xor(c1, d);
      c2 += __shfl_xor(c2, d);
      c3 += __shfl_xor(c3, d);
    }
    if (lane == 0) {
      uint32_t p1 = (uint32_t)min(c1, 255), p2 = (uint32_t)min(c2, 255),
               p3 = (uint32_t)min(c3, 255);
      chunkoff[row] = p1 | (p2 << 8) | (p3 << 16);
    }
    for (int i = lane; i < cnt; i += 64) {
      uint2 e = esw[b0 + i];
      float dout = deg_out[e.x];
      float nw = __uint_as_float(e.y) / sqrtf(fmaxf(dout * s, 1e-12f));
      esw[b0 + i] = make_uint2(e.x, __float_as_uint(nw));
    }
  }
}

// ---------------- format conversion ----------------

__global__ void k_pack4(const float* __restrict__ in, uint32_t* __restrict__ Xp,
                        uint32_t* __restrict__ Xb, int n4) {
  int i = blockIdx.x * 256 + threadIdx.x;
  if (i >= n4) return;
  float4 f = ((const float4*)in)[i];
  ((uint4*)Xp)[i] = make_uint4(pack_hl(f.x), pack_hl(f.y), pack_hl(f.z), pack_hl(f.w));
  uint2 b;
  b.x = f2bf_rn(f.x) | (f2bf_rn(f.y) << 16);
  b.y = f2bf_rn(f.z) | (f2bf_rn(f.w) << 16);
  ((uint2*)Xb)[i] = b;
}

__global__ void k_packW(const float* __restrict__ p0, const float* __restrict__ p1,
                        const float* __restrict__ p2, const float* __restrict__ p3,
                        const float* __restrict__ p4, ushort_t* __restrict__ out) {
  int i = blockIdx.x * 256 + threadIdx.x;
  if (i >= 180224) return;
  float f;
  if (i < 49152) f = p0[i];
  else if (i < 98304) f = p1[i - 49152];
  else if (i < 147456) f = p2[i - 98304];
  else if (i < 163840) f = p3[i - 147456];
  else f = p4[i - 163840];
  out[i] = (ushort_t)f2bf_rn(f);
}

// ---------------- chunked SpMM (plain launch, no sync) ----------------------
// 8 contiguous rows per wave; chunk-major loop keeps the chip's active waves
// in a ~3.2MB src window (per-XCD L2). fp32 accums live in registers; row
// metadata reloaded per (chunk,row) from L2. Edge lists are wave-uniform
// (scalar path).

__global__ __launch_bounds__(256) void k_spmm_chunk(
    const uint32_t* __restrict__ X, uint32_t* __restrict__ Y,
    const uint2* __restrict__ esw, const int* __restrict__ rowptr,
    const uint32_t* __restrict__ chunkoff, int n) {
  const int lane = threadIdx.x & 63;
  int gw = (int)(blockIdx.x * 4 + (threadIdx.x >> 6));
  gw = __builtin_amdgcn_readfirstlane(gw);
  const int r0 = gw * RPW;

  float a0[RPW], a1[RPW];
#pragma unroll
  for (int k = 0; k < RPW; ++k) { a0[k] = 0.f; a1[k] = 0.f; }

  for (int c = 0; c < 4; ++c) {
#pragma unroll
    for (int k = 0; k < RPW; ++k) {
      int row = r0 + k;
      if (row < n) {
        int b0 = rowptr[row];
        int cnt = rowptr[row + 1] - b0;
        uint32_t off = chunkoff[row];
        int i0 = (c == 0) ? 0 : (int)((off >> (8 * c - 8)) & 255u);
        int i1 = (c == 3) ? cnt : (int)((off >> (8 * c)) & 255u);
        const uint2* __restrict__ ep = esw + b0;
        int i = i0;
        for (; i + 4 <= i1; i += 4) {
          uint2 e0 = ep[i], e1 = ep[i + 1], e2 = ep[i + 2], e3 = ep[i + 3];
          uint32_t u0 = X[(size_t)e0.x * 64 + lane];
          uint32_t u1 = X[(size_t)e1.x * 64 + lane];
          uint32_t u2 = X[(size_t)e2.x * 64 + lane];
          uint32_t u3 = X[(size_t)e3.x * 64 + lane];
          float w0 = __uint_as_float(e0.y), w1 = __uint_as_float(e1.y);
          float w2 = __uint_as_float(e2.y), w3 = __uint_as_float(e3.y);
          a0[k] = fmaf(w0, bflo(u0), a0[k]); a1[k] = fmaf(w0, bfhi(u0), a1[k]);
          a0[k] = fmaf(w1, bflo(u1), a0[k]); a1[k] = fmaf(w1, bfhi(u1), a1[k]);
          a0[k] = fmaf(w2, bflo(u2), a0[k]); a1[k] = fmaf(w2, bfhi(u2), a1[k]);
          a0[k] = fmaf(w3, bflo(u3), a0[k]); a1[k] = fmaf(w3, bfhi(u3), a1[k]);
        }
        for (; i < i1; ++i) {
          uint2 e = ep[i];
          uint32_t u = X[(size_t)e.x * 64 + lane];
          float w0 = __uint_as_float(e.y);
          a0[k] = fmaf(w0, bflo(u), a0[k]);
          a1[k] = fmaf(w0, bfhi(u), a1[k]);
        }
      }
    }
  }

#pragma unroll
  for (int k = 0; k < RPW; ++k) {
    int row = r0 + k;
    if (row < n)
      Y[(size_t)row * 64 + lane] = f2bf_rn(a0[k]) | (f2bf_rn(a1[k]) << 16);
  }
}

// ---------------- MFMA GEMM --------------------------------------------------

__device__ __forceinline__ void build_frags_v(uint4 q0, uint4 q1, v8bf& hi, v8bf& lo) {
  BFU uh, ul;
  uh.u[0] = (q0.x >> 16) | (q0.y & 0xffff0000u);
  uh.u[1] = (q0.z >> 16) | (q0.w & 0xffff0000u);
  uh.u[2] = (q1.x >> 16) | (q1.y & 0xffff0000u);
  uh.u[3] = (q1.z >> 16) | (q1.w & 0xffff0000u);
  ul.u[0] = (q0.x & 0xffffu) | (q0.y << 16);
  ul.u[1] = (q0.z & 0xffffu) | (q0.w << 16);
  ul.u[2] = (q1.x & 0xffffu) | (q1.y << 16);
  ul.u[3] = (q1.z & 0xffffu) | (q1.w << 16);
  hi = uh.b;
  lo = ul.b;
}

__global__ __launch_bounds__(256) void k_gemm(
    const uint32_t* __restrict__ F0hl, const uint32_t* __restrict__ F1b,
    const uint32_t* __restrict__ F2b, const ushort_t* __restrict__ Wb,
    const float* __restrict__ bias, int relu, int M,
    uint32_t* __restrict__ outp, ushort_t* __restrict__ outh,
    float* __restrict__ outf) {
  __shared__ ushort_t Wl[128 * 128];  // 32 KB swizzled
  const int t = threadIdx.x;
  const int lane = t & 63;
  const int wave = t >> 6;
  const int wr = wave >> 1, wc = wave & 1;
  const int row0 = blockIdx.x * 64;
  const int l15 = lane & 15;
  const int kg = lane >> 4;

  int arow[2];
#pragma unroll
  for (int mr = 0; mr < 2; ++mr)
    arow[mr] = min(row0 + wr * 32 + mr * 16 + l15, M - 1);
  int wcol[4];
  float bv[4];
#pragma unroll
  for (int nr = 0; nr < 4; ++nr) {
    wcol[nr] = wc * 64 + nr * 16 + l15;
    bv[nr] = bias[wcol[nr]];
  }

  const uint32_t* __restrict__ F0r0 = F0hl + (size_t)arow[0] * D128 + kg * 8;
  const uint32_t* __restrict__ F0r1 = F0hl + (size_t)arow[1] * D128 + kg * 8;
  const uint32_t* __restrict__ F1r0 = F1b + (size_t)arow[0] * 64 + kg * 4;
  const uint32_t* __restrict__ F1r1 = F1b + (size_t)arow[1] * 64 + kg * 4;
  const uint32_t* __restrict__ F2r0 = F2b + (size_t)arow[0] * 64 + kg * 4;
  const uint32_t* __restrict__ F2r1 = F2b + (size_t)arow[1] * 64 + kg * 4;

  v4f acc[2][4];
#pragma unroll
  for (int mr = 0; mr < 2; ++mr)
#pragma unroll
    for (int nr = 0; nr < 4; ++nr) acc[mr][nr] = (v4f){0.f, 0.f, 0.f, 0.f};

  const int sc = t >> 1;
  const int sh = t & 1;
  const ushort_t* gpW = Wb + (size_t)sc * 384 + sh * 64;
  char* WlBase = (char*)Wl + sc * 256;

  // ---------------- seg0 (hi/lo plane, 2 MFMA per frag) ----------------
  uint4 f0[4][2][2];
#pragma unroll
  for (int kc = 0; kc < 2; ++kc) {
    f0[kc][0][0] = *(const uint4*)(F0r0 + kc * 32);
    f0[kc][0][1] = *(const uint4*)(F0r0 + kc * 32 + 4);
    f0[kc][1][0] = *(const uint4*)(F0r1 + kc * 32);
    f0[kc][1][1] = *(const uint4*)(F0r1 + kc * 32 + 4);
  }
  __syncthreads();
  {
    const ushort_t* gp = gpW;
#pragma unroll
    for (int gi = 0; gi < 8; ++gi) {
      int gg = sh * 8 + gi;
      uint4 v = *(const uint4*)(gp + gi * 8);
      *(uint4*)(WlBase + ((gg ^ (sc & 7)) * 16)) = v;
    }
  }
  __syncthreads();
#pragma unroll
  for (int kc = 0; kc < 4; ++kc) {
    if (kc < 2) {
      f0[kc + 2][0][0] = *(const uint4*)(F0r0 + (kc + 2) * 32);
      f0[kc + 2][0][1] = *(const uint4*)(F0r0 + (kc + 2) * 32 + 4);
      f0[kc + 2][1][0] = *(const uint4*)(F0r1 + (kc + 2) * 32);
      f0[kc + 2][1][1] = *(const uint4*)(F0r1 + (kc + 2) * 32 + 4);
    }
    v8bf ah[2], al[2];
#pragma unroll
    for (int mr = 0; mr < 2; ++mr)
      build_frags_v(f0[kc][mr][0], f0[kc][mr][1], ah[mr], al[mr]);
#pragma unroll
    for (int nr = 0; nr < 4; ++nr) {
      int col = wcol[nr];
      int g = (kc << 2) + kg;
      v8bf bf = *(const v8bf*)((const char*)Wl + col * 256 + ((g ^ (col & 7)) * 16));
#pragma unroll
      for (int mr = 0; mr < 2; ++mr) {
        acc[mr][nr] = __builtin_amdgcn_mfma_f32_16x16x32_bf16(ah[mr], bf, acc[mr][nr], 0, 0, 0);
        acc[mr][nr] = __builtin_amdgcn_mfma_f32_16x16x32_bf16(al[mr], bf, acc[mr][nr], 0, 0, 0);
      }
    }
  }

  // ---------------- seg1, seg2 (bf16 planes, full preload) ----------------
#pragma unroll
  for (int seg = 1; seg < 3; ++seg) {
    const uint32_t* __restrict__ Fr0 = (seg == 1) ? F1r0 : F2r0;
    const uint32_t* __restrict__ Fr1 = (seg == 1) ? F1r1 : F2r1;
    uint4 fb[4][2];
#pragma unroll
    for (int kc = 0; kc < 4; ++kc) {
      fb[kc][0] = *(const uint4*)(Fr0 + kc * 16);
      fb[kc][1] = *(const uint4*)(Fr1 + kc * 16);
    }
    __syncthreads();
    {
      const ushort_t* gp = gpW + seg * 128;
#pragma unroll
      for (int gi = 0; gi < 8; ++gi) {
        int gg = sh * 8 + gi;
        uint4 v = *(const uint4*)(gp + gi * 8);
        *(uint4*)(WlBase + ((gg ^ (sc & 7)) * 16)) = v;
      }
    }
    __syncthreads();
#pragma unroll
    for (int kc = 0; kc < 4; ++kc) {
      v8bf af[2];
      {
        BFU u0, u1;
        u0.q = fb[kc][0];
        u1.q = fb[kc][1];
        af[0] = u0.b;
        af[1] = u1.b;
      }
#pragma unroll
      for (int nr = 0; nr < 4; ++nr) {
        int col = wcol[nr];
        int g = (kc << 2) + kg;
        v8bf bf = *(const v8bf*)((const char*)Wl + col * 256 + ((g ^ (col & 7)) * 16));
#pragma unroll
        for (int mr = 0; mr < 2; ++mr)
          acc[mr][nr] = __builtin_amdgcn_mfma_f32_16x16x32_bf16(af[mr], bf, acc[mr][nr], 0, 0, 0);
      }
    }
  }

  __syncthreads();  // all reads done before (possibly aliased) epilogue writes

#pragma unroll
  for (int mr = 0; mr < 2; ++mr) {
#pragma unroll
    for (int nr = 0; nr < 4; ++nr) {
      v4f a = acc[mr][nr];
#pragma unroll
      for (int r = 0; r < 4; ++r) {
        int row = row0 + wr * 32 + mr * 16 + kg * 4 + r;
        if (row < M) {
          float v = a[r] + bv[nr];
          if (relu) v = fmaxf(v, 0.f);
          size_t o = (size_t)row * D128 + wcol[nr];
          if (outp) outp[o] = pack_hl(v);
          if (outh) outh[o] = (ushort_t)f2bf_rn(v);
          if (outf) outf[o] = v;
        }
      }
    }
  }
}

// ---------------- fused predictor (128 pairs/block, 2 chunks) ----------------

__global__ __launch_bounds__(256) void k_pred(
    const uint32_t* __restrict__ Hb, const int* __restrict__ pos_src,
    const int* __restrict__ pos_dst, const int* __restrict__ neg_src,
    const int* __restrict__ neg_dst, const ushort_t* __restrict__ W1,
    const ushort_t* __restrict__ W2, const float* __restrict__ b1,
    const float* __restrict__ b2, const float* __restrict__ w3,
    const float* __restrict__ b3, int P, float* __restrict__ out) {
  __shared__ ushort_t Wl[128 * 128];
  const int t = threadIdx.x;
  const int lane = t & 63;
  const int wave = t >> 6;
  const int l15 = lane & 15;
  const int kg = lane >> 4;
  const int P2 = 2 * P;

  const int qA = blockIdx.x * 128 + wave * 16 + l15;
  const int qB = qA + 64;
  const bool vA = qA < P2, vB = qB < P2;
  const int qcA = vA ? qA : (P2 - 1);
  const int qcB = vB ? qB : (P2 - 1);
  const int iaA = (qcA < P) ? pos_src[qcA] : neg_src[qcA - P];
  const int ibA = (qcA < P) ? pos_dst[qcA] : neg_dst[qcA - P];
  const int iaB = (qcB < P) ? pos_src[qcB] : neg_src[qcB - P];
  const int ibB = (qcB < P) ? pos_dst[qcB] : neg_dst[qcB - P];

  const int sc = t >> 1;
  const int sh = t & 1;

  // ---- stage W1 ----
  {
    const ushort_t* gp = W1 + sc * 128 + sh * 64;
#pragma unroll
    for (int gi = 0; gi < 8; ++gi) {
      int gg = sh * 8 + gi;
      uint4 v = *(const uint4*)(gp + gi * 8);
      *(uint4*)((char*)Wl + sc * 256 + ((gg ^ (sc & 7)) * 16)) = v;
    }
  }

  // ---- gather both chunks (32 independent 16B loads in flight) ----
  uint4 gaA[4], gbA[4], gaB[4], gbB[4];
#pragma unroll
  for (int kc = 0; kc < 4; ++kc) {
    gaA[kc] = *(const uint4*)(Hb + (size_t)iaA * 64 + kc * 16 + kg * 4);
    gbA[kc] = *(const uint4*)(Hb + (size_t)ibA * 64 + kc * 16 + kg * 4);
    gaB[kc] = *(const uint4*)(Hb + (size_t)iaB * 64 + kc * 16 + kg * 4);
    gbB[kc] = *(const uint4*)(Hb + (size_t)ibB * 64 + kc * 16 + kg * 4);
  }
  v8bf zfA[4], zfB[4];
#pragma unroll
  for (int kc = 0; kc < 4; ++kc) {
    BFU zA, zB;
    zA.u[0] = bfmul2(gaA[kc].x, gbA[kc].x);
    zA.u[1] = bfmul2(gaA[kc].y, gbA[kc].y);
    zA.u[2] = bfmul2(gaA[kc].z, gbA[kc].z);
    zA.u[3] = bfmul2(gaA[kc].w, gbA[kc].w);
    zB.u[0] = bfmul2(gaB[kc].x, gbB[kc].x);
    zB.u[1] = bfmul2(gaB[kc].y, gbB[kc].y);
    zB.u[2] = bfmul2(gaB[kc].z, gbB[kc].z);
    zB.u[3] = bfmul2(gaB[kc].w, gbB[kc].w);
    zfA[kc] = zA.b;
    zfB[kc] = zB.b;
  }
  __syncthreads();

  // ---- layer 1, chunk A then chunk B ----
  uint32_t pkA[8][2], pkB[8][2];
  {
    v4f acc1[8];
#pragma unroll
    for (int nr = 0; nr < 8; ++nr) acc1[nr] = (v4f){0.f, 0.f, 0.f, 0.f};
#pragma unroll
    for (int kc = 0; kc < 4; ++kc) {
#pragma unroll
      for (int nr = 0; nr < 8; ++nr) {
        int c = nr * 16 + l15;
        int g = 4 * kc + kg;
        v8bf wf = *(const v8bf*)((const char*)Wl + c * 256 + ((g ^ (c & 7)) * 16));
        acc1[nr] = __builtin_amdgcn_mfma_f32_16x16x32_bf16(wf, zfA[kc], acc1[nr], 0, 0, 0);
      }
    }
#pragma unroll
    for (int nr = 0; nr < 8; ++nr) {
      float v0 = fmaxf(acc1[nr][0] + b1[nr * 16 + kg * 4 + 0], 0.f);
      float v1 = fmaxf(acc1[nr][1] + b1[nr * 16 + kg * 4 + 1], 0.f);
      float v2 = fmaxf(acc1[nr][2] + b1[nr * 16 + kg * 4 + 2], 0.f);
      float v3 = fmaxf(acc1[nr][3] + b1[nr * 16 + kg * 4 + 3], 0.f);
      pkA[nr][0] = f2bf_rn(v0) | (f2bf_rn(v1) << 16);
      pkA[nr][1] = f2bf_rn(v2) | (f2bf_rn(v3) << 16);
    }
  }
  {
    v4f acc1[8];
#pragma unroll
    for (int nr = 0; nr < 8; ++nr) acc1[nr] = (v4f){0.f, 0.f, 0.f, 0.f};
#pragma unroll
    for (int kc = 0; kc < 4; ++kc) {
#pragma unroll
      for (int nr = 0; nr < 8; ++nr) {
        int c = nr * 16 + l15;
        int g = 4 * kc + kg;
        v8bf wf = *(const v8bf*)((const char*)Wl + c * 256 + ((g ^ (c & 7)) * 16));
        acc1[nr] = __builtin_amdgcn_mfma_f32_16x16x32_bf16(wf, zfB[kc], acc1[nr], 0, 0, 0);
      }
    }
#pragma unroll
    for (int nr = 0; nr < 8; ++nr) {
      float v0 = fmaxf(acc1[nr][0] + b1[nr * 16 + kg * 4 + 0], 0.f);
      float v1 = fmaxf(acc1[nr][1] + b1[nr * 16 + kg * 4 + 1], 0.f);
      float v2 = fmaxf(acc1[nr][2] + b1[nr * 16 + kg * 4 + 2], 0.f);
      float v3 = fmaxf(acc1[nr][3] + b1[nr * 16 + kg * 4 + 3], 0.f);
      pkB[nr][0] = f2bf_rn(v0) | (f2bf_rn(v1) << 16);
      pkB[nr][1] = f2bf_rn(v2) | (f2bf_rn(v3) << 16);
    }
  }

  // ---- restage W2 ----
  __syncthreads();
  {
    const ushort_t* gp = W2 + sc * 128 + sh * 64;
#pragma unroll
    for (int gi = 0; gi < 8; ++gi) {
      int gg = sh * 8 + gi;
      uint4 v = *(const uint4*)(gp + gi * 8);
      *(uint4*)((char*)Wl + sc * 256 + ((gg ^ (sc & 7)) * 16)) = v;
    }
  }
  __syncthreads();

  // ---- layer 2 + dot, chunk A then chunk B ----
#pragma unroll
  for (int chunk = 0; chunk < 2; ++chunk) {
    v4f acc2[8];
#pragma unroll
    for (int nr = 0; nr < 8; ++nr) acc2[nr] = (v4f){0.f, 0.f, 0.f, 0.f};
#pragma unroll
    for (int kc = 0; kc < 4; ++kc) {
      BFU y;
#pragma unroll
      for (int d = 0; d < 4; ++d) {
        int srcLane = l15 + 16 * ((kg & 1) * 2 + (d >> 1));
        uint32_t w0, w1;
        if (chunk == 0) {
          w0 = (uint32_t)__shfl((int)pkA[2 * kc][d & 1], srcLane);
          w1 = (uint32_t)__shfl((int)pkA[2 * kc + 1][d & 1], srcLane);
        } else {
          w0 = (uint32_t)__shfl((int)pkB[2 * kc][d & 1], srcLane);
          w1 = (uint32_t)__shfl((int)pkB[2 * kc + 1][d & 1], srcLane);
        }
        y.u[d] = (kg & 2) ? w1 : w0;
      }
#pragma unroll
      for (int nr = 0; nr < 8; ++nr) {
        int c = nr * 16 + l15;
        int g = 4 * kc + kg;
        v8bf wf = *(const v8bf*)((const char*)Wl + c * 256 + ((g ^ (c & 7)) * 16));
        acc2[nr] = __builtin_amdgcn_mfma_f32_16x16x32_bf16(wf, y.b, acc2[nr], 0, 0, 0);
      }
    }
    float s = 0.f;
#pragma unroll
    for (int nr = 0; nr < 8; ++nr) {
#pragma unroll
      for (int r = 0; r < 4; ++r) {
        int c = nr * 16 + kg * 4 + r;
        s += fmaxf(acc2[nr][r] + b2[c], 0.f) * w3[c];
      }
    }
    s += __shfl_xor(s, 16);
    s += __shfl_xor(s, 32);
    if (chunk == 0) {
      if (vA && kg == 0) out[qA] = s + b3[0];
    } else {
      if (vB && kg == 0) out[qB] = s + b3[0];
    }
  }
}

// ---------------- launch ----------------

extern "C" void kernel_launch(void* const* d_in, const int* in_sizes, int n_in,
                              void* d_out, int out_size, void* d_ws, size_t ws_size,
                              hipStream_t stream) {
  const float* x = (const float*)d_in[0];
  const float* w = (const float*)d_in[1];
  const int* src = (const int*)d_in[2];
  const int* dst = (const int*)d_in[3];
  const int* pos_src = (const int*)d_in[4];
  const int* pos_dst = (const int*)d_in[5];
  const int* neg_src = (const int*)d_in[6];
  const int* neg_dst = (const int*)d_in[7];
  const float* W0 = (const float*)d_in[8];
  const float* b0 = (const float*)d_in[9];
  const float* W1 = (const float*)d_in[10];
  const float* b1 = (const float*)d_in[11];
  const float* W2 = (const float*)d_in[12];
  const float* b2 = (const float*)d_in[13];
  const float* Wp1 = (const float*)d_in[14];
  const float* bp1 = (const float*)d_in[15];
  const float* Wp2 = (const float*)d_in[16];
  const float* bp2 = (const float*)d_in[17];
  const float* Wp3 = (const float*)d_in[18];
  const float* bp3 = (const float*)d_in[19];

  const int N = in_sizes[0] / D128;
  const int E = in_sizes[1];
  const int P = in_sizes[4];

  float* out = (float*)d_out;
  float* h_fin = out + 2 * (size_t)P;   // [N,128] fp32 final h (d_out)
  uint32_t* Hp = (uint32_t*)h_fin;      // reused as hi/lo h1 scratch

  char* p = (char*)d_ws;
#define WALLOC(T, name, bytes) \
  T name = (T)p;               \
  p += (((size_t)(bytes) + 255) & ~(size_t)255);
  WALLOC(uint32_t*, meta, (size_t)(4 * 256 + 2 * 257) * 4)
  WALLOC(float*, deg_out, (size_t)N * 4)
  WALLOC(int*, rowptr, (size_t)(N + 1) * 4)
  WALLOC(uint32_t*, chunkoff, (size_t)N * 4)
  WALLOC(uint2*, bufD, (size_t)E * 8)
  WALLOC(uint2*, bufS, (size_t)E * 8)
  WALLOC(uint2*, esw, (size_t)E * 8)
  WALLOC(ushort_t*, Wpk, (size_t)180224 * 2)
  WALLOC(uint32_t*, Xp, (size_t)N * D128 * 4)   // hi/lo: x, then h2
  WALLOC(uint32_t*, Xb, (size_t)N * 64 * 4)     // bf16 x
  WALLOC(uint32_t*, A, (size_t)N * 64 * 4)      // bf16 hop-1 result
  WALLOC(uint32_t*, B, (size_t)N * 64 * 4)      // bf16 hop-2 result / h3 plane
  WALLOC(uint32_t*, Hbuf, (size_t)N * 64 * 4)   // bf16 h1/h2 plane
#undef WALLOC

  uint32_t* histD = meta;
  uint32_t* histS = meta + 256;
  uint32_t* curD = meta + 512;
  uint32_t* curS = meta + 768;
  uint32_t* baseD = meta + 1024;
  uint32_t* baseS = meta + 1024 + 257;

  const ushort_t* W0b = Wpk;
  const ushort_t* W1b = Wpk + 49152;
  const ushort_t* W2b = Wpk + 98304;
  const ushort_t* Wp1b = Wpk + 147456;
  const ushort_t* Wp2b = Wpk + 163840;

  const int rb = (N + 3) / 4;
  const int gg = (N + 63) / 64;
  const int nHi = (N + 255) >> 8;
  const int spmm_blocks = (N + RPW * 4 - 1) / (RPW * 4);

  // ---- sort-based graph build ----
  hipMemsetAsync(meta, 0, 4 * 256 * 4, stream);
  k_hist2<<<128, 256, 0, stream>>>(src, dst, E, histD, histS);
  k_scan2<<<1, 256, 0, stream>>>(histD, histS, curD, baseD, curS, baseS, rowptr, N, E);
  k_part_dst<<<128, 256, 0, stream>>>(src, dst, w, E, curD, bufD);
  k_part_src<<<128, 256, 0, stream>>>(src, w, E, curS, bufS);
  k_sub_dst<<<nHi, 256, 0, stream>>>(bufD, baseD, esw, rowptr, N);
  k_sub_src<<<nHi, 256, 0, stream>>>(bufS, baseS, deg_out, N);
  k_norm<<<rb, 256, 0, stream>>>(deg_out, rowptr, esw, chunkoff, N);

  // ---- pack inputs ----
  k_pack4<<<(N * 32 + 255) / 256, 256, 0, stream>>>(x, Xp, Xb, N * 32);
  k_packW<<<(180224 + 255) / 256, 256, 0, stream>>>(W0, W1, W2, Wp1, Wp2, Wpk);

  // ---- layer 1: (Xp, Xb) -> h1 in (Hp hi/lo, Hbuf bf16) ----
  k_spmm_chunk<<<spmm_blocks, 256, 0, stream>>>(Xb, A, esw, rowptr, chunkoff, N);
  k_spmm_chunk<<<spmm_blocks, 256, 0, stream>>>(A, B, esw, rowptr, chunkoff, N);
  k_gemm<<<gg, 256, 0, stream>>>(Xp, A, B, W0b, b0, 1, N, Hp, (ushort_t*)Hbuf, nullptr);
  // ---- layer 2: (Hp, Hbuf) -> h2 in (Xp hi/lo, Hbuf bf16) ----
  k_spmm_chunk<<<spmm_blocks, 256, 0, stream>>>(Hbuf, A, esw, rowptr, chunkoff, N);
  k_spmm_chunk<<<spmm_blocks, 256, 0, stream>>>(A, B, esw, rowptr, chunkoff, N);
  k_gemm<<<gg, 256, 0, stream>>>(Hp, A, B, W1b, b1, 1, N, Xp, (ushort_t*)Hbuf, nullptr);
  // ---- layer 3: (Xp, Hbuf) -> h3 fp32 in h_fin + bf16 plane in B (alias) ----
  k_spmm_chunk<<<spmm_blocks, 256, 0, stream>>>(Hbuf, A, esw, rowptr, chunkoff, N);
  k_spmm_chunk<<<spmm_blocks, 256, 0, stream>>>(A, B, esw, rowptr, chunkoff, N);
  k_gemm<<<gg, 256, 0, stream>>>(Xp, A, B, W2b, b2, 0, N, nullptr, (ushort_t*)B, h_fin);

  // ---- fused predictor over pos+neg (2P pairs) ----
  k_pred<<<(2 * P + 127) / 128, 256, 0, stream>>>(B, pos_src, pos_dst, neg_src, neg_dst,
                                                  Wp1b, Wp2b, bp1, bp2, Wp3, bp3, P, out);
}

// Round 12
// 422.224 us; speedup vs baseline: 10.0234x; 1.2838x over previous
//
#include <hip/hip_runtime.h>
#include <stdint.h>

// ---------------------------------------------------------------------------
// TAGConv(3 layers, K=2) + edge-weight norm + MLP link predictor.
// Round 12: revert to R8 structure (best: 446us). Locality experiments
// (R9-R11) closed: chunking cut FETCH 3.5x but not time -> SpMM is gather
// issue/latency bound. New: 16-deep independent gather batches in k_spmm
// (edge payloads ride SGPRs; 16 VGPRs of in-flight data), merged partition
// kernel (one pass over src/dst/w).
// ---------------------------------------------------------------------------

#define D128 128

typedef __bf16 v8bf __attribute__((ext_vector_type(8)));
typedef float v4f __attribute__((ext_vector_type(4)));
typedef uint32_t v4u __attribute__((ext_vector_type(4)));
typedef unsigned short ushort_t;

union BFU { v4u u; v8bf b; uint4 q; };

__device__ __forceinline__ uint32_t pack_hl(float f) {
  uint32_t hi = __float_as_uint(f) & 0xffff0000u;
  float lo = f - __uint_as_float(hi);
  return hi | (__float_as_uint(lo) >> 16);
}
__device__ __forceinline__ uint32_t f2bf_rn(float f) {
  uint32_t u = __float_as_uint(f);
  return (u + 0x7fffu + ((u >> 16) & 1u)) >> 16;
}
__device__ __forceinline__ float bflo(uint32_t u) { return __uint_as_float(u << 16); }
__device__ __forceinline__ float bfhi(uint32_t u) { return __uint_as_float(u & 0xffff0000u); }
__device__ __forceinline__ uint32_t bfmul2(uint32_t a, uint32_t b) {
  return f2bf_rn(bflo(a) * bflo(b)) | (f2bf_rn(bfhi(a) * bfhi(b)) << 16);
}

// ---------------- sort-based graph build ------------------------------------

__global__ void k_hist2(const int* __restrict__ src, const int* __restrict__ dst,
                        int E, uint32_t* __restrict__ histD,
                        uint32_t* __restrict__ histS) {
  __shared__ uint32_t hd[256], hs[256];
  int t = threadIdx.x;
  hd[t] = 0; hs[t] = 0;
  __syncthreads();
  for (int e = blockIdx.x * 256 + t; e < E; e += gridDim.x * 256) {
    atomicAdd(&hd[((unsigned)dst[e]) >> 8], 1u);
    atomicAdd(&hs[((unsigned)src[e]) >> 8], 1u);
  }
  __syncthreads();
  if (hd[t]) atomicAdd(&histD[t], hd[t]);
  if (hs[t]) atomicAdd(&histS[t], hs[t]);
}

__global__ void k_scan2(const uint32_t* __restrict__ histD,
                        const uint32_t* __restrict__ histS,
                        uint32_t* __restrict__ curD, uint32_t* __restrict__ baseD,
                        uint32_t* __restrict__ curS, uint32_t* __restrict__ baseS,
                        int* __restrict__ rowptr, int N, int E) {
  __shared__ uint32_t ws[4];
  int t = threadIdx.x;
  int lane = t & 63, wid = t >> 6;
  for (int which = 0; which < 2; ++which) {
    uint32_t v = which ? histS[t] : histD[t];
    uint32_t x = v;
#pragma unroll
    for (int d = 1; d < 64; d <<= 1) {
      uint32_t y = (uint32_t)__shfl_up((int)x, d);
      if (lane >= d) x += y;
    }
    if (lane == 63) ws[wid] = x;
    __syncthreads();
    if (t == 0) {
      uint32_t a = 0;
#pragma unroll
      for (int k = 0; k < 4; ++k) { uint32_t tmp = ws[k]; ws[k] = a; a += tmp; }
    }
    __syncthreads();
    uint32_t ex = x - v + ws[wid];
    if (which == 0) {
      curD[t] = ex; baseD[t] = ex;
      if (t == 0) baseD[256] = (uint32_t)E;
    } else {
      curS[t] = ex; baseS[t] = ex;
      if (t == 0) baseS[256] = (uint32_t)E;
    }
    __syncthreads();
  }
  if (t == 0) rowptr[N] = E;
}

// merged partition: one pass over src/dst/w, both bucket sets
__global__ void k_part2(const int* __restrict__ src, const int* __restrict__ dst,
                        const float* __restrict__ w, int E,
                        uint32_t* __restrict__ curD, uint32_t* __restrict__ curS,
                        uint2* __restrict__ bufD, uint2* __restrict__ bufS) {
  __shared__ uint32_t lhD[256], lbD[256], lhS[256], lbS[256];
  int t = threadIdx.x;
  int per = (E + gridDim.x - 1) / gridDim.x;
  int e0 = blockIdx.x * per, e1 = min(e0 + per, E);
  lhD[t] = 0; lhS[t] = 0;
  __syncthreads();
  for (int e = e0 + t; e < e1; e += 256) {
    atomicAdd(&lhD[((unsigned)dst[e]) >> 8], 1u);
    atomicAdd(&lhS[((unsigned)src[e]) >> 8], 1u);
  }
  __syncthreads();
  uint32_t cD = lhD[t], cS = lhS[t];
  lbD[t] = cD ? atomicAdd(&curD[t], cD) : 0u;
  lbS[t] = cS ? atomicAdd(&curS[t], cS) : 0u;
  __syncthreads();
  lhD[t] = 0; lhS[t] = 0;
  __syncthreads();
  for (int e = e0 + t; e < e1; e += 256) {
    int s = src[e], d = dst[e];
    uint32_t wb = __float_as_uint(w[e]);
    uint32_t binD = ((unsigned)d) >> 8;
    uint32_t posD = lbD[binD] + atomicAdd(&lhD[binD], 1u);
    bufD[posD] = make_uint2((((unsigned)d & 255u) << 16) | (unsigned)s, wb);
    uint32_t binS = ((unsigned)s) >> 8;
    uint32_t posS = lbS[binS] + atomicAdd(&lhS[binS], 1u);
    bufS[posS] = make_uint2((unsigned)s, wb);
  }
}

__global__ void k_sub_dst(const uint2* __restrict__ bufD,
                          const uint32_t* __restrict__ baseD,
                          uint2* __restrict__ esw, int* __restrict__ rowptr, int N) {
  __shared__ uint32_t lh[256], cur[256], ws4[4];
  int hb = blockIdx.x, t = threadIdx.x;
  int b = (int)baseD[hb], e = (int)baseD[hb + 1];
  lh[t] = 0;
  __syncthreads();
  for (int i = b + t; i < e; i += 256) atomicAdd(&lh[(bufD[i].x >> 16) & 255u], 1u);
  __syncthreads();
  uint32_t v = lh[t], x = v;
  int lane = t & 63, wid = t >> 6;
#pragma unroll
  for (int d = 1; d < 64; d <<= 1) {
    uint32_t y = (uint32_t)__shfl_up((int)x, d);
    if (lane >= d) x += y;
  }
  if (lane == 63) ws4[wid] = x;
  __syncthreads();
  if (t == 0) {
    uint32_t a = 0;
#pragma unroll
    for (int k = 0; k < 4; ++k) { uint32_t tmp = ws4[k]; ws4[k] = a; a += tmp; }
  }
  __syncthreads();
  uint32_t ex = x - v + ws4[wid];
  cur[t] = ex;
  int d = hb * 256 + t;
  if (d < N) rowptr[d] = b + (int)ex;
  __syncthreads();
  for (int i = b + t; i < e; i += 256) {
    uint2 el = bufD[i];
    uint32_t lo = (el.x >> 16) & 255u;
    uint32_t pos = atomicAdd(&cur[lo], 1u);
    esw[b + pos] = make_uint2(el.x & 0xffffu, el.y);
  }
}

__global__ void k_sub_src(const uint2* __restrict__ bufS,
                          const uint32_t* __restrict__ baseS,
                          float* __restrict__ deg_out, int N) {
  __shared__ float acc[256];
  int hb = blockIdx.x, t = threadIdx.x;
  acc[t] = 0.f;
  __syncthreads();
  int b = (int)baseS[hb], e = (int)baseS[hb + 1];
  for (int i = b + t; i < e; i += 256)
    atomicAdd(&acc[bufS[i].x & 255u], __uint_as_float(bufS[i].y));
  __syncthreads();
  int s = hb * 256 + t;
  if (s < N) deg_out[s] = acc[t];
}

__global__ void k_norm(const float* __restrict__ deg_out, const int* __restrict__ rowptr,
                       uint2* __restrict__ esw, int n) {
  int row = blockIdx.x * 4 + (threadIdx.x >> 6);
  if (row >= n) return;
  int lane = threadIdx.x & 63;
  int b0 = rowptr[row];
  int cnt = rowptr[row + 1] - b0;
  if (cnt <= 64) {
    uint32_t key = 0xffffffffu;
    float val = 0.f;
    if (lane < cnt) {
      uint2 e = esw[b0 + lane];
      key = e.x;
      val = __uint_as_float(e.y);
    }
    float s = val;
#pragma unroll
    for (int d = 32; d; d >>= 1) s += __shfl_xor(s, d);
#pragma unroll
    for (int k = 2; k <= 64; k <<= 1) {
#pragma unroll
      for (int j = k >> 1; j > 0; j >>= 1) {
        uint32_t ok = (uint32_t)__shfl_xor((int)key, j);
        float ov = __shfl_xor(val, j);
        bool asc = ((lane & k) == 0);
        bool lower = ((lane & j) == 0);
        bool take_min = (lower == asc);
        bool sw = take_min ? (ok < key) : (ok > key);
        if (sw) { key = ok; val = ov; }
      }
    }
    if (lane < cnt) {
      float dout = deg_out[key];
      float nw = val / sqrtf(fmaxf(dout * s, 1e-12f));
      esw[b0 + lane] = make_uint2(key, __float_as_uint(nw));
    }
  } else {
    float s = 0.f;
    for (int i = lane; i < cnt; i += 64) s += __uint_as_float(esw[b0 + i].y);
#pragma unroll
    for (int d = 32; d; d >>= 1) s += __shfl_xor(s, d);
    for (int i = lane; i < cnt; i += 64) {
      uint2 e = esw[b0 + i];
      float dout = deg_out[e.x];
      float nw = __uint_as_float(e.y) / sqrtf(fmaxf(dout * s, 1e-12f));
      esw[b0 + i] = make_uint2(e.x, __float_as_uint(nw));
    }
  }
}

// ---------------- format conversion ----------------

__global__ void k_pack4(const float* __restrict__ in, uint32_t* __restrict__ Xp,
                        uint32_t* __restrict__ Xb, int n4) {
  int i = blockIdx.x * 256 + threadIdx.x;
  if (i >= n4) return;
  float4 f = ((const float4*)in)[i];
  ((uint4*)Xp)[i] = make_uint4(pack_hl(f.x), pack_hl(f.y), pack_hl(f.z), pack_hl(f.w));
  uint2 b;
  b.x = f2bf_rn(f.x) | (f2bf_rn(f.y) << 16);
  b.y = f2bf_rn(f.z) | (f2bf_rn(f.w) << 16);
  ((uint2*)Xb)[i] = b;
}

__global__ void k_packW(const float* __restrict__ p0, const float* __restrict__ p1,
                        const float* __restrict__ p2, const float* __restrict__ p3,
                        const float* __restrict__ p4, ushort_t* __restrict__ out) {
  int i = blockIdx.x * 256 + threadIdx.x;
  if (i >= 180224) return;
  float f;
  if (i < 49152) f = p0[i];
  else if (i < 98304) f = p1[i - 49152];
  else if (i < 147456) f = p2[i - 98304];
  else if (i < 163840) f = p3[i - 147456];
  else f = p4[i - 163840];
  out[i] = (ushort_t)f2bf_rn(f);
}

// ---------------- SpMM: CSR, 16-deep gather batches -------------------------
// One wave per dst row (readfirstlane-uniform -> edge list on scalar path).
// Batch of 16 independent gathers in flight (16 VGPRs), then FMAs.

__global__ __launch_bounds__(256) void k_spmm(
    const uint32_t* __restrict__ X, uint32_t* __restrict__ Y,
    const uint2* __restrict__ esw, const int* __restrict__ rowptr, int n) {
  int row = blockIdx.x * 4 + (threadIdx.x >> 6);
  if (row >= n) return;
  row = __builtin_amdgcn_readfirstlane(row);
  int lane = threadIdx.x & 63;
  int b0 = rowptr[row];
  int cnt = rowptr[row + 1] - b0;
  const uint2* __restrict__ ep = esw + b0;
  const uint32_t* __restrict__ Xl = X + lane;
  float a0 = 0.f, a1 = 0.f, c0 = 0.f, c1 = 0.f;
  int i = 0;
  for (; i + 16 <= cnt; i += 16) {
    uint2 e[16];
#pragma unroll
    for (int j = 0; j < 16; ++j) e[j] = ep[i + j];
    uint32_t u[16];
#pragma unroll
    for (int j = 0; j < 16; ++j) u[j] = Xl[(size_t)e[j].x * 64];
#pragma unroll
    for (int j = 0; j < 16; j += 2) {
      float w0 = __uint_as_float(e[j].y);
      float w1 = __uint_as_float(e[j + 1].y);
      a0 = fmaf(w0, bflo(u[j]), a0);
      a1 = fmaf(w0, bfhi(u[j]), a1);
      c0 = fmaf(w1, bflo(u[j + 1]), c0);
      c1 = fmaf(w1, bfhi(u[j + 1]), c1);
    }
  }
  for (; i + 4 <= cnt; i += 4) {
    uint2 e[4];
#pragma unroll
    for (int j = 0; j < 4; ++j) e[j] = ep[i + j];
    uint32_t u[4];
#pragma unroll
    for (int j = 0; j < 4; ++j) u[j] = Xl[(size_t)e[j].x * 64];
#pragma unroll
    for (int j = 0; j < 4; j += 2) {
      float w0 = __uint_as_float(e[j].y);
      float w1 = __uint_as_float(e[j + 1].y);
      a0 = fmaf(w0, bflo(u[j]), a0);
      a1 = fmaf(w0, bfhi(u[j]), a1);
      c0 = fmaf(w1, bflo(u[j + 1]), c0);
      c1 = fmaf(w1, bfhi(u[j + 1]), c1);
    }
  }
  for (; i < cnt; ++i) {
    uint2 e = ep[i];
    uint32_t u = Xl[(size_t)e.x * 64];
    float w0 = __uint_as_float(e.y);
    a0 = fmaf(w0, bflo(u), a0);
    a1 = fmaf(w0, bfhi(u), a1);
  }
  Y[(size_t)row * 64 + lane] = f2bf_rn(a0 + c0) | (f2bf_rn(a1 + c1) << 16);
}

// ---------------- MFMA GEMM --------------------------------------------------

__device__ __forceinline__ void build_frags_v(uint4 q0, uint4 q1, v8bf& hi, v8bf& lo) {
  BFU uh, ul;
  uh.u[0] = (q0.x >> 16) | (q0.y & 0xffff0000u);
  uh.u[1] = (q0.z >> 16) | (q0.w & 0xffff0000u);
  uh.u[2] = (q1.x >> 16) | (q1.y & 0xffff0000u);
  uh.u[3] = (q1.z >> 16) | (q1.w & 0xffff0000u);
  ul.u[0] = (q0.x & 0xffffu) | (q0.y << 16);
  ul.u[1] = (q0.z & 0xffffu) | (q0.w << 16);
  ul.u[2] = (q1.x & 0xffffu) | (q1.y << 16);
  ul.u[3] = (q1.z & 0xffffu) | (q1.w << 16);
  hi = uh.b;
  lo = ul.b;
}

__global__ __launch_bounds__(256) void k_gemm(
    const uint32_t* __restrict__ F0hl, const uint32_t* __restrict__ F1b,
    const uint32_t* __restrict__ F2b, const ushort_t* __restrict__ Wb,
    const float* __restrict__ bias, int relu, int M,
    uint32_t* __restrict__ outp, ushort_t* __restrict__ outh,
    float* __restrict__ outf) {
  __shared__ ushort_t Wl[128 * 128];  // 32 KB swizzled
  const int t = threadIdx.x;
  const int lane = t & 63;
  const int wave = t >> 6;
  const int wr = wave >> 1, wc = wave & 1;
  const int row0 = blockIdx.x * 64;
  const int l15 = lane & 15;
  const int kg = lane >> 4;

  int arow[2];
#pragma unroll
  for (int mr = 0; mr < 2; ++mr)
    arow[mr] = min(row0 + wr * 32 + mr * 16 + l15, M - 1);
  int wcol[4];
  float bv[4];
#pragma unroll
  for (int nr = 0; nr < 4; ++nr) {
    wcol[nr] = wc * 64 + nr * 16 + l15;
    bv[nr] = bias[wcol[nr]];
  }

  const uint32_t* __restrict__ F0r0 = F0hl + (size_t)arow[0] * D128 + kg * 8;
  const uint32_t* __restrict__ F0r1 = F0hl + (size_t)arow[1] * D128 + kg * 8;
  const uint32_t* __restrict__ F1r0 = F1b + (size_t)arow[0] * 64 + kg * 4;
  const uint32_t* __restrict__ F1r1 = F1b + (size_t)arow[1] * 64 + kg * 4;
  const uint32_t* __restrict__ F2r0 = F2b + (size_t)arow[0] * 64 + kg * 4;
  const uint32_t* __restrict__ F2r1 = F2b + (size_t)arow[1] * 64 + kg * 4;

  v4f acc[2][4];
#pragma unroll
  for (int mr = 0; mr < 2; ++mr)
#pragma unroll
    for (int nr = 0; nr < 4; ++nr) acc[mr][nr] = (v4f){0.f, 0.f, 0.f, 0.f};

  const int sc = t >> 1;
  const int sh = t & 1;
  const ushort_t* gpW = Wb + (size_t)sc * 384 + sh * 64;
  char* WlBase = (char*)Wl + sc * 256;

  // ---------------- seg0 (hi/lo plane, 2 MFMA per frag) ----------------
  uint4 f0[4][2][2];
#pragma unroll
  for (int kc = 0; kc < 2; ++kc) {
    f0[kc][0][0] = *(const uint4*)(F0r0 + kc * 32);
    f0[kc][0][1] = *(const uint4*)(F0r0 + kc * 32 + 4);
    f0[kc][1][0] = *(const uint4*)(F0r1 + kc * 32);
    f0[kc][1][1] = *(const uint4*)(F0r1 + kc * 32 + 4);
  }
  __syncthreads();
  {
    const ushort_t* gp = gpW;
#pragma unroll
    for (int gi = 0; gi < 8; ++gi) {
      int gg = sh * 8 + gi;
      uint4 v = *(const uint4*)(gp + gi * 8);
      *(uint4*)(WlBase + ((gg ^ (sc & 7)) * 16)) = v;
    }
  }
  __syncthreads();
#pragma unroll
  for (int kc = 0; kc < 4; ++kc) {
    if (kc < 2) {
      f0[kc + 2][0][0] = *(const uint4*)(F0r0 + (kc + 2) * 32);
      f0[kc + 2][0][1] = *(const uint4*)(F0r0 + (kc + 2) * 32 + 4);
      f0[kc + 2][1][0] = *(const uint4*)(F0r1 + (kc + 2) * 32);
      f0[kc + 2][1][1] = *(const uint4*)(F0r1 + (kc + 2) * 32 + 4);
    }
    v8bf ah[2], al[2];
#pragma unroll
    for (int mr = 0; mr < 2; ++mr)
      build_frags_v(f0[kc][mr][0], f0[kc][mr][1], ah[mr], al[mr]);
#pragma unroll
    for (int nr = 0; nr < 4; ++nr) {
      int col = wcol[nr];
      int g = (kc << 2) + kg;
      v8bf bf = *(const v8bf*)((const char*)Wl + col * 256 + ((g ^ (col & 7)) * 16));
#pragma unroll
      for (int mr = 0; mr < 2; ++mr) {
        acc[mr][nr] = __builtin_amdgcn_mfma_f32_16x16x32_bf16(ah[mr], bf, acc[mr][nr], 0, 0, 0);
        acc[mr][nr] = __builtin_amdgcn_mfma_f32_16x16x32_bf16(al[mr], bf, acc[mr][nr], 0, 0, 0);
      }
    }
  }

  // ---------------- seg1, seg2 (bf16 planes, full preload) ----------------
#pragma unroll
  for (int seg = 1; seg < 3; ++seg) {
    const uint32_t* __restrict__ Fr0 = (seg == 1) ? F1r0 : F2r0;
    const uint32_t* __restrict__ Fr1 = (seg == 1) ? F1r1 : F2r1;
    uint4 fb[4][2];
#pragma unroll
    for (int kc = 0; kc < 4; ++kc) {
      fb[kc][0] = *(const uint4*)(Fr0 + kc * 16);
      fb[kc][1] = *(const uint4*)(Fr1 + kc * 16);
    }
    __syncthreads();
    {
      const ushort_t* gp = gpW + seg * 128;
#pragma unroll
      for (int gi = 0; gi < 8; ++gi) {
        int gg = sh * 8 + gi;
        uint4 v = *(const uint4*)(gp + gi * 8);
        *(uint4*)(WlBase + ((gg ^ (sc & 7)) * 16)) = v;
      }
    }
    __syncthreads();
#pragma unroll
    for (int kc = 0; kc < 4; ++kc) {
      v8bf af[2];
      {
        BFU u0, u1;
        u0.q = fb[kc][0];
        u1.q = fb[kc][1];
        af[0] = u0.b;
        af[1] = u1.b;
      }
#pragma unroll
      for (int nr = 0; nr < 4; ++nr) {
        int col = wcol[nr];
        int g = (kc << 2) + kg;
        v8bf bf = *(const v8bf*)((const char*)Wl + col * 256 + ((g ^ (col & 7)) * 16));
#pragma unroll
        for (int mr = 0; mr < 2; ++mr)
          acc[mr][nr] = __builtin_amdgcn_mfma_f32_16x16x32_bf16(af[mr], bf, acc[mr][nr], 0, 0, 0);
      }
    }
  }

  __syncthreads();  // all reads done before (possibly aliased) epilogue writes

#pragma unroll
  for (int mr = 0; mr < 2; ++mr) {
#pragma unroll
    for (int nr = 0; nr < 4; ++nr) {
      v4f a = acc[mr][nr];
#pragma unroll
      for (int r = 0; r < 4; ++r) {
        int row = row0 + wr * 32 + mr * 16 + kg * 4 + r;
        if (row < M) {
          float v = a[r] + bv[nr];
          if (relu) v = fmaxf(v, 0.f);
          size_t o = (size_t)row * D128 + wcol[nr];
          if (outp) outp[o] = pack_hl(v);
          if (outh) outh[o] = (ushort_t)f2bf_rn(v);
          if (outf) outf[o] = v;
        }
      }
    }
  }
}

// ---------------- fused predictor (128 pairs/block, 2 chunks) ----------------

__global__ __launch_bounds__(256) void k_pred(
    const uint32_t* __restrict__ Hb, const int* __restrict__ pos_src,
    const int* __restrict__ pos_dst, const int* __restrict__ neg_src,
    const int* __restrict__ neg_dst, const ushort_t* __restrict__ W1,
    const ushort_t* __restrict__ W2, const float* __restrict__ b1,
    const float* __restrict__ b2, const float* __restrict__ w3,
    const float* __restrict__ b3, int P, float* __restrict__ out) {
  __shared__ ushort_t Wl[128 * 128];
  const int t = threadIdx.x;
  const int lane = t & 63;
  const int wave = t >> 6;
  const int l15 = lane & 15;
  const int kg = lane >> 4;
  const int P2 = 2 * P;

  const int qA = blockIdx.x * 128 + wave * 16 + l15;
  const int qB = qA + 64;
  const bool vA = qA < P2, vB = qB < P2;
  const int qcA = vA ? qA : (P2 - 1);
  const int qcB = vB ? qB : (P2 - 1);
  const int iaA = (qcA < P) ? pos_src[qcA] : neg_src[qcA - P];
  const int ibA = (qcA < P) ? pos_dst[qcA] : neg_dst[qcA - P];
  const int iaB = (qcB < P) ? pos_src[qcB] : neg_src[qcB - P];
  const int ibB = (qcB < P) ? pos_dst[qcB] : neg_dst[qcB - P];

  const int sc = t >> 1;
  const int sh = t & 1;

  // ---- stage W1 ----
  {
    const ushort_t* gp = W1 + sc * 128 + sh * 64;
#pragma unroll
    for (int gi = 0; gi < 8; ++gi) {
      int gg = sh * 8 + gi;
      uint4 v = *(const uint4*)(gp + gi * 8);
      *(uint4*)((char*)Wl + sc * 256 + ((gg ^ (sc & 7)) * 16)) = v;
    }
  }

  // ---- gather both chunks (32 independent 16B loads in flight) ----
  uint4 gaA[4], gbA[4], gaB[4], gbB[4];
#pragma unroll
  for (int kc = 0; kc < 4; ++kc) {
    gaA[kc] = *(const uint4*)(Hb + (size_t)iaA * 64 + kc * 16 + kg * 4);
    gbA[kc] = *(const uint4*)(Hb + (size_t)ibA * 64 + kc * 16 + kg * 4);
    gaB[kc] = *(const uint4*)(Hb + (size_t)iaB * 64 + kc * 16 + kg * 4);
    gbB[kc] = *(const uint4*)(Hb + (size_t)ibB * 64 + kc * 16 + kg * 4);
  }
  v8bf zfA[4], zfB[4];
#pragma unroll
  for (int kc = 0; kc < 4; ++kc) {
    BFU zA, zB;
    zA.u[0] = bfmul2(gaA[kc].x, gbA[kc].x);
    zA.u[1] = bfmul2(gaA[kc].y, gbA[kc].y);
    zA.u[2] = bfmul2(gaA[kc].z, gbA[kc].z);
    zA.u[3] = bfmul2(gaA[kc].w, gbA[kc].w);
    zB.u[0] = bfmul2(gaB[kc].x, gbB[kc].x);
    zB.u[1] = bfmul2(gaB[kc].y, gbB[kc].y);
    zB.u[2] = bfmul2(gaB[kc].z, gbB[kc].z);
    zB.u[3] = bfmul2(gaB[kc].w, gbB[kc].w);
    zfA[kc] = zA.b;
    zfB[kc] = zB.b;
  }
  __syncthreads();

  // ---- layer 1, chunk A then chunk B ----
  uint32_t pkA[8][2], pkB[8][2];
  {
    v4f acc1[8];
#pragma unroll
    for (int nr = 0; nr < 8; ++nr) acc1[nr] = (v4f){0.f, 0.f, 0.f, 0.f};
#pragma unroll
    for (int kc = 0; kc < 4; ++kc) {
#pragma unroll
      for (int nr = 0; nr < 8; ++nr) {
        int c = nr * 16 + l15;
        int g = 4 * kc + kg;
        v8bf wf = *(const v8bf*)((const char*)Wl + c * 256 + ((g ^ (c & 7)) * 16));
        acc1[nr] = __builtin_amdgcn_mfma_f32_16x16x32_bf16(wf, zfA[kc], acc1[nr], 0, 0, 0);
      }
    }
#pragma unroll
    for (int nr = 0; nr < 8; ++nr) {
      float v0 = fmaxf(acc1[nr][0] + b1[nr * 16 + kg * 4 + 0], 0.f);
      float v1 = fmaxf(acc1[nr][1] + b1[nr * 16 + kg * 4 + 1], 0.f);
      float v2 = fmaxf(acc1[nr][2] + b1[nr * 16 + kg * 4 + 2], 0.f);
      float v3 = fmaxf(acc1[nr][3] + b1[nr * 16 + kg * 4 + 3], 0.f);
      pkA[nr][0] = f2bf_rn(v0) | (f2bf_rn(v1) << 16);
      pkA[nr][1] = f2bf_rn(v2) | (f2bf_rn(v3) << 16);
    }
  }
  {
    v4f acc1[8];
#pragma unroll
    for (int nr = 0; nr < 8; ++nr) acc1[nr] = (v4f){0.f, 0.f, 0.f, 0.f};
#pragma unroll
    for (int kc = 0; kc < 4; ++kc) {
#pragma unroll
      for (int nr = 0; nr < 8; ++nr) {
        int c = nr * 16 + l15;
        int g = 4 * kc + kg;
        v8bf wf = *(const v8bf*)((const char*)Wl + c * 256 + ((g ^ (c & 7)) * 16));
        acc1[nr] = __builtin_amdgcn_mfma_f32_16x16x32_bf16(wf, zfB[kc], acc1[nr], 0, 0, 0);
      }
    }
#pragma unroll
    for (int nr = 0; nr < 8; ++nr) {
      float v0 = fmaxf(acc1[nr][0] + b1[nr * 16 + kg * 4 + 0], 0.f);
      float v1 = fmaxf(acc1[nr][1] + b1[nr * 16 + kg * 4 + 1], 0.f);
      float v2 = fmaxf(acc1[nr][2] + b1[nr * 16 + kg * 4 + 2], 0.f);
      float v3 = fmaxf(acc1[nr][3] + b1[nr * 16 + kg * 4 + 3], 0.f);
      pkB[nr][0] = f2bf_rn(v0) | (f2bf_rn(v1) << 16);
      pkB[nr][1] = f2bf_rn(v2) | (f2bf_rn(v3) << 16);
    }
  }

  // ---- restage W2 ----
  __syncthreads();
  {
    const ushort_t* gp = W2 + sc * 128 + sh * 64;
#pragma unroll
    for (int gi = 0; gi < 8; ++gi) {
      int gg = sh * 8 + gi;
      uint4 v = *(const uint4*)(gp + gi * 8);
      *(uint4*)((char*)Wl + sc * 256 + ((gg ^ (sc & 7)) * 16)) = v;
    }
  }
  __syncthreads();

  // ---- layer 2 + dot, chunk A then chunk B ----
#pragma unroll
  for (int chunk = 0; chunk < 2; ++chunk) {
    v4f acc2[8];
#pragma unroll
    for (int nr = 0; nr < 8; ++nr) acc2[nr] = (v4f){0.f, 0.f, 0.f, 0.f};
#pragma unroll
    for (int kc = 0; kc < 4; ++kc) {
      BFU y;
#pragma unroll
      for (int d = 0; d < 4; ++d) {
        int srcLane = l15 + 16 * ((kg & 1) * 2 + (d >> 1));
        uint32_t w0, w1;
        if (chunk == 0) {
          w0 = (uint32_t)__shfl((int)pkA[2 * kc][d & 1], srcLane);
          w1 = (uint32_t)__shfl((int)pkA[2 * kc + 1][d & 1], srcLane);
        } else {
          w0 = (uint32_t)__shfl((int)pkB[2 * kc][d & 1], srcLane);
          w1 = (uint32_t)__shfl((int)pkB[2 * kc + 1][d & 1], srcLane);
        }
        y.u[d] = (kg & 2) ? w1 : w0;
      }
#pragma unroll
      for (int nr = 0; nr < 8; ++nr) {
        int c = nr * 16 + l15;
        int g = 4 * kc + kg;
        v8bf wf = *(const v8bf*)((const char*)Wl + c * 256 + ((g ^ (c & 7)) * 16));
        acc2[nr] = __builtin_amdgcn_mfma_f32_16x16x32_bf16(wf, y.b, acc2[nr], 0, 0, 0);
      }
    }
    float s = 0.f;
#pragma unroll
    for (int nr = 0; nr < 8; ++nr) {
#pragma unroll
      for (int r = 0; r < 4; ++r) {
        int c = nr * 16 + kg * 4 + r;
        s += fmaxf(acc2[nr][r] + b2[c], 0.f) * w3[c];
      }
    }
    s += __shfl_xor(s, 16);
    s += __shfl_xor(s, 32);
    if (chunk == 0) {
      if (vA && kg == 0) out[qA] = s + b3[0];
    } else {
      if (vB && kg == 0) out[qB] = s + b3[0];
    }
  }
}

// ---------------- launch ----------------

extern "C" void kernel_launch(void* const* d_in, const int* in_sizes, int n_in,
                              void* d_out, int out_size, void* d_ws, size_t ws_size,
                              hipStream_t stream) {
  const float* x = (const float*)d_in[0];
  const float* w = (const float*)d_in[1];
  const int* src = (const int*)d_in[2];
  const int* dst = (const int*)d_in[3];
  const int* pos_src = (const int*)d_in[4];
  const int* pos_dst = (const int*)d_in[5];
  const int* neg_src = (const int*)d_in[6];
  const int* neg_dst = (const int*)d_in[7];
  const float* W0 = (const float*)d_in[8];
  const float* b0 = (const float*)d_in[9];
  const float* W1 = (const float*)d_in[10];
  const float* b1 = (const float*)d_in[11];
  const float* W2 = (const float*)d_in[12];
  const float* b2 = (const float*)d_in[13];
  const float* Wp1 = (const float*)d_in[14];
  const float* bp1 = (const float*)d_in[15];
  const float* Wp2 = (const float*)d_in[16];
  const float* bp2 = (const float*)d_in[17];
  const float* Wp3 = (const float*)d_in[18];
  const float* bp3 = (const float*)d_in[19];

  const int N = in_sizes[0] / D128;
  const int E = in_sizes[1];
  const int P = in_sizes[4];

  float* out = (float*)d_out;
  float* h_fin = out + 2 * (size_t)P;   // [N,128] fp32 final h (d_out)
  uint32_t* Hp = (uint32_t*)h_fin;      // reused as hi/lo h1 scratch

  char* p = (char*)d_ws;
#define WALLOC(T, name, bytes) \
  T name = (T)p;               \
  p += (((size_t)(bytes) + 255) & ~(size_t)255);
  WALLOC(uint32_t*, meta, (size_t)(4 * 256 + 2 * 257) * 4)
  WALLOC(float*, deg_out, (size_t)N * 4)
  WALLOC(int*, rowptr, (size_t)(N + 1) * 4)
  WALLOC(uint2*, bufD, (size_t)E * 8)
  WALLOC(uint2*, bufS, (size_t)E * 8)
  WALLOC(uint2*, esw, (size_t)E * 8)
  WALLOC(ushort_t*, Wpk, (size_t)180224 * 2)
  WALLOC(uint32_t*, Xp, (size_t)N * D128 * 4)   // hi/lo: x, then h2
  WALLOC(uint32_t*, Xb, (size_t)N * 64 * 4)     // bf16 x
  WALLOC(uint32_t*, A, (size_t)N * 64 * 4)      // bf16 hop-1 result
  WALLOC(uint32_t*, B, (size_t)N * 64 * 4)      // bf16 hop-2 result / h3 plane
  WALLOC(uint32_t*, Hbuf, (size_t)N * 64 * 4)   // bf16 h1/h2 plane
#undef WALLOC

  uint32_t* histD = meta;
  uint32_t* histS = meta + 256;
  uint32_t* curD = meta + 512;
  uint32_t* curS = meta + 768;
  uint32_t* baseD = meta + 1024;
  uint32_t* baseS = meta + 1024 + 257;

  const ushort_t* W0b = Wpk;
  const ushort_t* W1b = Wpk + 49152;
  const ushort_t* W2b = Wpk + 98304;
  const ushort_t* Wp1b = Wpk + 147456;
  const ushort_t* Wp2b = Wpk + 163840;

  const int rb = (N + 3) / 4;
  const int gg = (N + 63) / 64;
  const int nHi = (N + 255) >> 8;

  // ---- sort-based graph build ----
  hipMemsetAsync(meta, 0, 4 * 256 * 4, stream);
  k_hist2<<<128, 256, 0, stream>>>(src, dst, E, histD, histS);
  k_scan2<<<1, 256, 0, stream>>>(histD, histS, curD, baseD, curS, baseS, rowptr, N, E);
  k_part2<<<128, 256, 0, stream>>>(src, dst, w, E, curD, curS, bufD, bufS);
  k_sub_dst<<<nHi, 256, 0, stream>>>(bufD, baseD, esw, rowptr, N);
  k_sub_src<<<nHi, 256, 0, stream>>>(bufS, baseS, deg_out, N);
  k_norm<<<rb, 256, 0, stream>>>(deg_out, rowptr, esw, N);

  // ---- pack inputs ----
  k_pack4<<<(N * 32 + 255) / 256, 256, 0, stream>>>(x, Xp, Xb, N * 32);
  k_packW<<<(180224 + 255) / 256, 256, 0, stream>>>(W0, W1, W2, Wp1, Wp2, Wpk);

  // ---- layer 1: (Xp, Xb) -> h1 in (Hp hi/lo, Hbuf bf16) ----
  k_spmm<<<rb, 256, 0, stream>>>(Xb, A, esw, rowptr, N);
  k_spmm<<<rb, 256, 0, stream>>>(A, B, esw, rowptr, N);
  k_gemm<<<gg, 256, 0, stream>>>(Xp, A, B, W0b, b0, 1, N, Hp, (ushort_t*)Hbuf, nullptr);
  // ---- layer 2: (Hp, Hbuf) -> h2 in (Xp hi/lo, Hbuf bf16) ----
  k_spmm<<<rb, 256, 0, stream>>>(Hbuf, A, esw, rowptr, N);
  k_spmm<<<rb, 256, 0, stream>>>(A, B, esw, rowptr, N);
  k_gemm<<<gg, 256, 0, stream>>>(Hp, A, B, W1b, b1, 1, N, Xp, (ushort_t*)Hbuf, nullptr);
  // ---- layer 3: (Xp, Hbuf) -> h3 fp32 in h_fin + bf16 plane in B (alias) ----
  k_spmm<<<rb, 256, 0, stream>>>(Hbuf, A, esw, rowptr, N);
  k_spmm<<<rb, 256, 0, stream>>>(A, B, esw, rowptr, N);
  k_gemm<<<gg, 256, 0, stream>>>(Xp, A, B, W2b, b2, 0, N, nullptr, (ushort_t*)B, h_fin);

  // ---- fused predictor over pos+neg (2P pairs) ----
  k_pred<<<(2 * P + 127) / 128, 256, 0, stream>>>(B, pos_src, pos_dst, neg_src, neg_dst,
                                                  Wp1b, Wp2b, bp1, bp2, Wp3, bp3, P, out);
}